// Round 10
// baseline (890.135 us; speedup 1.0000x reference)
//
#include <hip/hip_runtime.h>

typedef __attribute__((ext_vector_type(8))) short  short8;
typedef __attribute__((ext_vector_type(4))) float  f32x4;
typedef __attribute__((ext_vector_type(4))) ushort us4;
typedef __attribute__((ext_vector_type(4))) uint   u32x4;
typedef __attribute__((ext_vector_type(2))) uint   u32x2;
typedef unsigned long long ull;

__device__ __forceinline__ float bf2f(ushort u) {
    union { uint i; float f; } c; c.i = ((uint)u) << 16; return c.f;
}
__device__ __forceinline__ float bits2f(uint b) {
    union { uint i; float f; } c; c.i = b; return c.f;
}
__device__ __forceinline__ ushort f2bf(float f) {
    union { float f; uint i; } c; c.f = f;
    uint b = c.i + 0x7fffu + ((c.i >> 16) & 1u);   // RNE, no NaN inputs here
    return (ushort)(b >> 16);
}

// ================= CSR build via LDS-binned counting sort ====================
// Contiguous padded CSR. Bucket b's padded region statically starts at
// bbase[b] + 192*b (per-node x4 padding adds <= 3*64 slots per bucket), so
// binDa can write rowptr directly and the second bucket scan is gone.
// binDa also histograms nodes by packet-count (64 bins) -> a degree-sorted
// permutation (round-9 lesson: wave trip = max degree over 16 nodes; sorting
// makes waves degree-uniform, removing ~30% wasted iterations in aggr).
#define NBLK  256     // blocks for histA/binC
#define NBMAX 1024    // max buckets of 64 nodes (N <= 65472)

__device__ __forceinline__
void histA_body(const int* __restrict__ col, int* __restrict__ counts,
                int E, int NB, uint* hist) {
    for (int j = threadIdx.x; j < NB; j += 256) hist[j] = 0u;
    __syncthreads();
    for (int i = blockIdx.x * 256 + threadIdx.x; i < E; i += 256 * NBLK)
        atomicAdd(&hist[((uint)col[i]) >> 6], 1u);
    __syncthreads();
    for (int j = threadIdx.x; j < NB; j += 256)
        counts[j * NBLK + blockIdx.x] = (int)hist[j];
}

__device__ __forceinline__
void binC_body(const int* __restrict__ row, const int* __restrict__ col,
               const float* __restrict__ w,
               const int* __restrict__ counts, const int* __restrict__ bbase,
               ull* __restrict__ recs, int E, int NB, uint* cur) {
    for (int j = threadIdx.x; j < NB; j += 256)
        cur[j] = (uint)(bbase[j] + counts[j * NBLK + blockIdx.x]);
    __syncthreads();
    for (int i = blockIdx.x * 256 + threadIdx.x; i < E; i += 256 * NBLK) {
        int c = col[i], r = row[i];
        float wv = w[i];
        uint w16 = (uint)(wv * 65536.0f);
        if (w16 > 65535u) w16 = 65535u;
        uint pos = atomicAdd(&cur[((uint)c) >> 6], 1u);
        recs[pos] = ((ull)(uint)c << 32) | (ull)((w16 << 16) | (uint)(r & 0xffff));
    }
}

// per bucket: per-node count/wsum -> dinv, padded count, rowptr (static bucket
// base + local scan), and the packet-count histogram for the degree sort.
__device__ __forceinline__
void binDa_body(const ull* __restrict__ recs, const int* __restrict__ bbase,
                int* __restrict__ cntp, float* __restrict__ dinv,
                int* __restrict__ rowptr, uint* __restrict__ pkhist, int N,
                uint* cnt, uint* ws, uint* arr) {
    int b = blockIdx.x, t = threadIdx.x;
    if (t < 64) { cnt[t] = 0u; ws[t] = 0u; }
    __syncthreads();
    int lo = bbase[b], hi = bbase[b + 1];
    for (int i = lo + t; i < hi; i += 256) {
        ull rec = recs[i];
        atomicAdd(&cnt[((uint)(rec >> 32)) & 63u], 1u);
        atomicAdd(&ws[((uint)(rec >> 32)) & 63u], (uint)((rec >> 16) & 0xffffu));
    }
    __syncthreads();
    int node = b * 64 + t;
    uint cp = 0;
    if (t < 64) {
        if (node < N) cp = (cnt[t] + 3u) & ~3u;
        arr[t] = cp;
    }
    __syncthreads();
    for (int off = 1; off < 64; off <<= 1) {
        uint x = (t < 64 && t >= off) ? arr[t - off] : 0u;
        __syncthreads();
        if (t < 64) arr[t] += x;
        __syncthreads();
    }
    if (t < 64 && node < N) {
        int base = bbase[b] + 192 * b;
        rowptr[node] = base + (int)(arr[t] - cp);
        cntp[node]   = (int)cp;
        dinv[node]   = rsqrtf(1.0f + (float)ws[t] * (1.0f / 65536.0f));
        uint key = cp >> 2;
        if (key > 63u) key = 63u;
        atomicAdd(&pkhist[key], 1u);
    }
}

// per bucket: place edges with packed bf16 norm at rowptr offsets; zero pads.
__device__ __forceinline__
void binDb_body(const ull* __restrict__ recs, const int* __restrict__ bbase,
                const int* __restrict__ rowptr, const int* __restrict__ cntp,
                const float* __restrict__ dinv, uint* __restrict__ edgesP, int N,
                uint* curN, uint* rbs, uint* cps) {
    int b = blockIdx.x, t = threadIdx.x;
    int node = b * 64 + t;
    if (t < 64) {
        uint rp = 0u, cp = 0u;
        if (node < N) { rp = (uint)rowptr[node]; cp = (uint)cntp[node]; }
        rbs[t] = rp; curN[t] = rp; cps[t] = cp;
    }
    __syncthreads();
    int lo = bbase[b], hi = bbase[b + 1];
    for (int i = lo + t; i < hi; i += 256) {
        ull rec = recs[i];
        uint c   = (uint)(rec >> 32);
        uint r   = (uint)rec & 0xffffu;
        uint w16 = ((uint)rec >> 16) & 0xffffu;
        float nv = dinv[r] * ((float)w16 * (1.0f / 65536.0f)) * dinv[c];
        uint slot = atomicAdd(&curN[c & 63u], 1u);
        edgesP[slot] = r | ((uint)f2bf(nv) << 16);
    }
    __syncthreads();
    if (t < 64 && node < N) {
        uint e1 = rbs[t] + cps[t];
        for (uint j = curN[t]; j < e1; ++j) edgesP[j] = 0u;  // nv=0, r=0 pad
    }
}

// degree-sort placement: pos from 64-bin cursor, perm[pos] = node.
__device__ __forceinline__
void permPlace_body(const int* __restrict__ cntp, uint* __restrict__ pkbase,
                    ushort* __restrict__ perm, int N, int blk) {
    int i = blk * 256 + (int)threadIdx.x;
    if (i < N) {
        uint key = ((uint)cntp[i]) >> 2;
        if (key > 63u) key = 63u;
        uint pos = atomicAdd(&pkbase[key], 1u);
        perm[pos] = (ushort)i;
    }
}

// exclusive scan of counts[b][0..255] in place; bucket totals out.
__global__ void k_scanB1(int* __restrict__ counts, int* __restrict__ btot) {
    __shared__ int s[256];
    int b = blockIdx.x, t = threadIdx.x;
    int v = counts[b * NBLK + t];
    s[t] = v; __syncthreads();
    for (int off = 1; off < 256; off <<= 1) {
        int x = (t >= off) ? s[t - off] : 0;
        __syncthreads();
        s[t] += x;
        __syncthreads();
    }
    counts[b * NBLK + t] = s[t] - v;
    if (t == 255) btot[b] = s[255];
}

// exclusive scan of up to 1023 totals -> base[0..NB]; also zeroes pkhist.
__global__ void k_scanB2(const int* __restrict__ btot, int* __restrict__ bbase,
                         int NB, uint* __restrict__ pkhist) {
    __shared__ int s[256];
    int t = threadIdx.x;
    if (t < 64) pkhist[t] = 0u;
    int v[4]; int sum = 0;
    #pragma unroll
    for (int j = 0; j < 4; ++j) {
        int i = t * 4 + j;
        v[j] = (i < NB) ? btot[i] : 0;
        sum += v[j];
    }
    s[t] = sum; __syncthreads();
    for (int off = 1; off < 256; off <<= 1) {
        int x = (t >= off) ? s[t - off] : 0;
        __syncthreads();
        s[t] += x;
        __syncthreads();
    }
    int excl = s[t] - sum;
    #pragma unroll
    for (int j = 0; j < 4; ++j) {
        int i = t * 4 + j;
        if (i <= NB) bbase[i] = excl;
        excl += v[j];
    }
}

// exclusive scan of the 64-bin degree histogram -> pkbase cursors.
__global__ void k_permScan(const uint* __restrict__ pkhist, uint* __restrict__ pkbase) {
    __shared__ uint s[64];
    int t = threadIdx.x;
    uint v = pkhist[t];
    s[t] = v; __syncthreads();
    for (int off = 1; off < 64; off <<= 1) {
        uint x = (t >= off) ? s[t - off] : 0u;
        __syncthreads();
        s[t] += x;
        __syncthreads();
    }
    pkbase[t] = s[t] - v;
}

// ================= weight split + transpose: W[K][N] -> WT{h,l}[N][K] ==========
__device__ __forceinline__
void splitT_body(const float* __restrict__ W, ushort* __restrict__ Th,
                 ushort* __restrict__ Tl, int K, int N, int i) {
    if (i < K * N) {
        int k = i / N, n = i - k * N;
        float v = W[i];
        ushort hi = f2bf(v);
        ushort lo = f2bf(v - bf2f(hi));
        Th[(size_t)n * K + k] = hi;
        Tl[(size_t)n * K + k] = lo;
    }
}

// ================= MFMA GEMM core =============================================
// Tile 128x128, BK=32, 256 thr = 4 waves (2x2), wave = 64x64 = 4x4 MFMA tiles.
// 3-product split precision: Ah*Bh + Ah*Bl + Al*Bh.
#define LDA 40   // padded LDS row stride (bf16 elems); 80 B = 5*16 keeps 16B align

__device__ __forceinline__
void gemm3_body(const float* __restrict__ A, const ushort* __restrict__ BTh,
                const ushort* __restrict__ BTl, ushort* __restrict__ Cpan,
                int M, int Nc, int K, int bm, int bn,
                ushort (*As)[128][LDA], ushort (*Bs)[128][LDA]) {
    const int t    = threadIdx.x;
    const int lane = t & 63;
    const int wid  = t >> 6;
    const int wm   = wid >> 1;
    const int wn   = wid & 1;
    const int ml   = lane & 15;
    const int kq   = lane >> 4;

    f32x4 acc[4][4];
    #pragma unroll
    for (int mt = 0; mt < 4; ++mt)
        #pragma unroll
        for (int nt = 0; nt < 4; ++nt) acc[mt][nt] = (f32x4){0.f, 0.f, 0.f, 0.f};

    for (int k0 = 0; k0 < K; k0 += 32) {
        #pragma unroll
        for (int it = 0; it < 4; ++it) {
            int idx = (t + it * 256) * 4;
            int r  = idx >> 5;
            int kk = idx & 31;
            int grow = bm + r;
            f32x4 v = (f32x4){0.f, 0.f, 0.f, 0.f};
            if (grow < M) v = *(const f32x4*)&A[(size_t)grow * K + k0 + kk];
            us4 hi, lo;
            #pragma unroll
            for (int j = 0; j < 4; ++j) {
                ushort h = f2bf(v[j]);
                hi[j] = h;
                lo[j] = f2bf(v[j] - bf2f(h));
            }
            *(us4*)&As[0][r][kk] = hi;
            *(us4*)&As[1][r][kk] = lo;
        }
        #pragma unroll
        for (int it = 0; it < 2; ++it) {
            int idx = (t + it * 256) * 8;
            int n  = idx >> 5;
            int kk = idx & 31;
            u32x4 vh = *(const u32x4*)&BTh[(size_t)(bn + n) * K + k0 + kk];
            *(u32x4*)&Bs[0][n][kk] = vh;
            u32x4 vl = *(const u32x4*)&BTl[(size_t)(bn + n) * K + k0 + kk];
            *(u32x4*)&Bs[1][n][kk] = vl;
        }
        __syncthreads();

        short8 a[4][2], b[4][2];
        #pragma unroll
        for (int mt = 0; mt < 4; ++mt) {
            a[mt][0] = *(const short8*)&As[0][wm * 64 + mt * 16 + ml][kq * 8];
            a[mt][1] = *(const short8*)&As[1][wm * 64 + mt * 16 + ml][kq * 8];
        }
        #pragma unroll
        for (int nt = 0; nt < 4; ++nt) {
            b[nt][0] = *(const short8*)&Bs[0][wn * 64 + nt * 16 + ml][kq * 8];
            b[nt][1] = *(const short8*)&Bs[1][wn * 64 + nt * 16 + ml][kq * 8];
        }
        #pragma unroll
        for (int mt = 0; mt < 4; ++mt)
            #pragma unroll
            for (int nt = 0; nt < 4; ++nt) {
                acc[mt][nt] = __builtin_amdgcn_mfma_f32_16x16x32_bf16(a[mt][0], b[nt][0], acc[mt][nt], 0, 0, 0);
                acc[mt][nt] = __builtin_amdgcn_mfma_f32_16x16x32_bf16(a[mt][0], b[nt][1], acc[mt][nt], 0, 0, 0);
                acc[mt][nt] = __builtin_amdgcn_mfma_f32_16x16x32_bf16(a[mt][1], b[nt][0], acc[mt][nt], 0, 0, 0);
            }
        __syncthreads();
    }

    #pragma unroll
    for (int mt = 0; mt < 4; ++mt) {
        int rbase = bm + wm * 64 + mt * 16 + kq * 4;
        #pragma unroll
        for (int nt = 0; nt < 4; ++nt) {
            int colg = bn + wn * 64 + nt * 16 + ml;
            size_t pbase = (size_t)(colg >> 5) * M * 32 + (colg & 31);
            #pragma unroll
            for (int r = 0; r < 4; ++r) {
                int rr = rbase + r;
                if (rr < M) Cpan[pbase + (size_t)rr * 32] = f2bf(acc[mt][nt][r]);
            }
        }
    }
}

__global__ __launch_bounds__(256)
void k_gemm3(const float* __restrict__ A, const ushort* __restrict__ BTh,
             const ushort* __restrict__ BTl, ushort* __restrict__ Cpan,
             int M, int Nc, int K) {
    __shared__ __align__(16) ushort As[2][128][LDA];
    __shared__ __align__(16) ushort Bs[2][128][LDA];
    gemm3_body(A, BTh, BTl, Cpan, M, Nc, K, blockIdx.y * 128, blockIdx.x * 128, As, Bs);
}

// ================= fused launches (binning || GEMM1 tiles) ===================
__global__ __launch_bounds__(256)
void k_fusedA(const int* __restrict__ col, int* __restrict__ counts, int E, int NB,
              const float* __restrict__ W1, ushort* __restrict__ WT1h, ushort* __restrict__ WT1l,
              int Fin, int H,
              const float* __restrict__ W2, ushort* __restrict__ WT2h, ushort* __restrict__ WT2l,
              int Fout, int sp1) {
    __shared__ uint hist[NBMAX];
    int bid = (int)blockIdx.x;
    if (bid < NBLK) { histA_body(col, counts, E, NB, hist); return; }
    if (bid < NBLK + sp1) { splitT_body(W1, WT1h, WT1l, Fin, H, (bid - NBLK) * 256 + (int)threadIdx.x); return; }
    splitT_body(W2, WT2h, WT2l, H, Fout, (bid - NBLK - sp1) * 256 + (int)threadIdx.x);
}

__global__ __launch_bounds__(256)
void k_fusedB1(const int* __restrict__ row, const int* __restrict__ col,
               const float* __restrict__ w, const int* __restrict__ counts,
               const int* __restrict__ bbase, ull* __restrict__ recs, int E, int NB,
               const float* __restrict__ A, const ushort* __restrict__ BTh,
               const ushort* __restrict__ BTl, ushort* __restrict__ Cpan,
               int M, int Nc, int K, int t0) {
    __shared__ __align__(16) ushort As[2][128][LDA];
    __shared__ __align__(16) ushort Bs[2][128][LDA];
    int bid = (int)blockIdx.x;
    if (bid < NBLK) { binC_body(row, col, w, counts, bbase, recs, E, NB, (uint*)&As[0][0][0]); return; }
    int tile = t0 + bid - NBLK;
    int nbn = Nc >> 7;
    gemm3_body(A, BTh, BTl, Cpan, M, Nc, K, (tile / nbn) * 128, (tile % nbn) * 128, As, Bs);
}

__global__ __launch_bounds__(256)
void k_fusedB2(const ull* __restrict__ recs, const int* __restrict__ bbase,
               int* __restrict__ cntp, float* __restrict__ dinv,
               int* __restrict__ rowptr, uint* __restrict__ pkhist,
               int N, int NB,
               const float* __restrict__ A, const ushort* __restrict__ BTh,
               const ushort* __restrict__ BTl, ushort* __restrict__ Cpan,
               int M, int Nc, int K, int t0) {
    __shared__ __align__(16) ushort As[2][128][LDA];
    __shared__ __align__(16) ushort Bs[2][128][LDA];
    int bid = (int)blockIdx.x;
    if (bid < NB) {
        uint* l = (uint*)&As[0][0][0];
        binDa_body(recs, bbase, cntp, dinv, rowptr, pkhist, N, l, l + 64, l + 128);
        return;
    }
    int tile = t0 + bid - NB;
    int nbn = Nc >> 7;
    gemm3_body(A, BTh, BTl, Cpan, M, Nc, K, (tile / nbn) * 128, (tile % nbn) * 128, As, Bs);
}

__global__ __launch_bounds__(256)
void k_fusedB3(const ull* __restrict__ recs, const int* __restrict__ bbase,
               const int* __restrict__ rowptr, const int* __restrict__ cntp,
               const float* __restrict__ dinv, uint* __restrict__ edgesP,
               uint* __restrict__ pkbase, ushort* __restrict__ perm,
               int N, int NB, int pp,
               const float* __restrict__ A, const ushort* __restrict__ BTh,
               const ushort* __restrict__ BTl, ushort* __restrict__ Cpan,
               int M, int Nc, int K, int t0) {
    __shared__ __align__(16) ushort As[2][128][LDA];
    __shared__ __align__(16) ushort Bs[2][128][LDA];
    int bid = (int)blockIdx.x;
    if (bid < NB) {
        uint* l = (uint*)&As[0][0][0];
        binDb_body(recs, bbase, rowptr, cntp, dinv, edgesP, N, l, l + 64, l + 128);
        return;
    }
    if (bid < NB + pp) { permPlace_body(cntp, pkbase, perm, N, bid - NB); return; }
    int tile = t0 + bid - NB - pp;
    int nbn = Nc >> 7;
    gemm3_body(A, BTh, BTl, Cpan, M, Nc, K, (tile / nbn) * 128, (tile % nbn) * 128, As, Bs);
}

// ================= panel CSR aggregation, butterfly-free =====================
// Panel-per-block (p = bid % npan): consecutive blocks round-robin XCDs so each
// XCD's L2 holds ONE 3.2 MB panel. Lanes: g=lane>>2 (16 nodes/wave), c=lane&3
// (8 feats/lane, one 16B dwordx4 gather; 4 lanes cover one 64B row).
// Nodes are taken through the degree-sorted perm so each wave's 16 nodes have
// ~equal edge counts (trip = mean, not max). Edge packets 4 at a time from one
// 16B-aligned dwordx4 (contiguous CSR, segments padded to x4).
#define NPB 64   // nodes per block: 4 waves x 16 nodes

template <bool RELU>
__device__ __forceinline__
void aggr_body(const ushort* __restrict__ perm, const int* __restrict__ rowptr,
               const int* __restrict__ cntp, const uint* __restrict__ edges,
               const ushort* __restrict__ hpan, const float* __restrict__ dinv,
               const float* __restrict__ bias, float* __restrict__ out,
               int F, int npan, int N) {
    const int bid  = blockIdx.x;
    const int p    = bid % npan;
    const int wave = threadIdx.x >> 6;
    const int lane = threadIdx.x & 63;
    const int g    = lane >> 2;        // node slot within wave (0..15)
    const int c    = lane & 3;         // feature octet within panel (0..3)
    const int idx  = (bid / npan) * NPB + wave * 16 + g;
    const int fbase = p * 32 + c * 8;

    const ushort* hp = hpan + (size_t)p * N * 32 + c * 8;   // + r*32 per gather

    int node = 0, beg = 0, end = 0;
    if (idx < N) {
        node = (int)perm[idx];
        beg = rowptr[node];
        end = beg + cntp[node];
    }

    float acc[8] = {};
    int e = beg;
    u32x4 pk4 = (u32x4){0u, 0u, 0u, 0u};
    if (e < end) pk4 = *(const u32x4*)&edges[e];
    while (__any(e < end)) {
        u32x4 cur = pk4;
        int e2 = e + 4;
        if (e2 < end) pk4 = *(const u32x4*)&edges[e2];   // prefetch next packet
        if (e < end) {
            #pragma unroll
            for (int j = 0; j < 4; ++j) {
                uint pk = cur[j];
                float nv = bits2f(pk & 0xffff0000u);
                int r = (int)(pk & 0xffffu);
                u32x4 hv = *(const u32x4*)(hp + (size_t)r * 32);
                #pragma unroll
                for (int q = 0; q < 4; ++q) {
                    acc[2 * q]     += nv * bits2f(hv[q] << 16);
                    acc[2 * q + 1] += nv * bits2f(hv[q] & 0xffff0000u);
                }
            }
        }
        e = e2;
    }

    if (idx < N) {
        float di = dinv[node];
        float d2 = di * di;
        u32x4 hs = *(const u32x4*)(hp + (size_t)node * 32);
        f32x4 bv0 = *(const f32x4*)&bias[fbase];
        f32x4 bv1 = *(const f32x4*)&bias[fbase + 4];
        f32x4 v0, v1;
        #pragma unroll
        for (int q = 0; q < 4; ++q) {
            float r0 = acc[2 * q]     + d2 * bits2f(hs[q] << 16)
                     + ((q < 2) ? bv0[2 * q] : bv1[2 * q - 4]);
            float r1 = acc[2 * q + 1] + d2 * bits2f(hs[q] & 0xffff0000u)
                     + ((q < 2) ? bv0[2 * q + 1] : bv1[2 * q - 3]);
            if (RELU) { r0 = fmaxf(r0, 0.f); r1 = fmaxf(r1, 0.f); }
            if (q < 2) { v0[2 * q] = r0; v0[2 * q + 1] = r1; }
            else       { v1[2 * q - 4] = r0; v1[2 * q - 3] = r1; }
        }
        *(f32x4*)&out[(size_t)node * F + fbase]     = v0;
        *(f32x4*)&out[(size_t)node * F + fbase + 4] = v1;
    }
}

__global__ __launch_bounds__(256)
void k_aggr1(const ushort* __restrict__ perm, const int* __restrict__ rowptr,
             const int* __restrict__ cntp, const uint* __restrict__ edges,
             const ushort* __restrict__ hpan, const float* __restrict__ dinv,
             const float* __restrict__ bias, float* __restrict__ out,
             int F, int npan, int N) {
    aggr_body<true>(perm, rowptr, cntp, edges, hpan, dinv, bias, out, F, npan, N);
}

__global__ __launch_bounds__(256)
void k_aggr2(const ushort* __restrict__ perm, const int* __restrict__ rowptr,
             const int* __restrict__ cntp, const uint* __restrict__ edges,
             const ushort* __restrict__ hpan, const float* __restrict__ dinv,
             const float* __restrict__ bias, float* __restrict__ out,
             int F, int npan, int N) {
    aggr_body<false>(perm, rowptr, cntp, edges, hpan, dinv, bias, out, F, npan, N);
}

// ================= launcher =================

static inline char* bump(char*& p, size_t bytes) {
    char* r = p;
    p += (bytes + 255) & ~(size_t)255;
    return r;
}

extern "C" void kernel_launch(void* const* d_in, const int* in_sizes, int n_in,
                              void* d_out, int out_size, void* d_ws, size_t ws_size,
                              hipStream_t stream) {
    const float* x  = (const float*)d_in[0];
    const int*   ei = (const int*)d_in[1];
    const float* ew = (const float*)d_in[2];
    const float* W1 = (const float*)d_in[3];
    const float* b1 = (const float*)d_in[4];
    const float* W2 = (const float*)d_in[5];
    const float* b2 = (const float*)d_in[6];
    float* out = (float*)d_out;

    const int E    = in_sizes[2];
    const int H    = in_sizes[4];       // 256
    const int Fout = in_sizes[6];       // 128
    const int Fin  = in_sizes[3] / H;   // 256
    const int N    = in_sizes[0] / Fin; // 50000 (fits ushort)
    const int NB   = (N + 63) >> 6;     // buckets of 64 nodes (<= 1023)

    const int* row = ei;
    const int* col = ei + E;

    char* p = (char*)d_ws;
    float*  dinv   = (float*)bump(p, (size_t)N * 4);
    int*    cntp   = (int*)bump(p, (size_t)N * 4);
    int*    rowptr = (int*)bump(p, (size_t)N * 4);
    ushort* perm   = (ushort*)bump(p, (size_t)N * 2);
    uint*   pkhist = (uint*)bump(p, 64 * 4);
    uint*   pkbase = (uint*)bump(p, 64 * 4);
    uint*   edgesP = (uint*)bump(p, ((size_t)E + 3 * N + 192 * (size_t)NBMAX + 256) * 4);
    int*    counts = (int*)bump(p, (size_t)NBMAX * NBLK * 4);
    int*    btot   = (int*)bump(p, (size_t)NBMAX * 4);
    int*    bbase  = (int*)bump(p, (size_t)(NBMAX + 1) * 4);
    ushort* WT1h   = (ushort*)bump(p, (size_t)Fin * H * 2);
    ushort* WT1l   = (ushort*)bump(p, (size_t)Fin * H * 2);
    ushort* WT2h   = (ushort*)bump(p, (size_t)H * Fout * 2);
    ushort* WT2l   = (ushort*)bump(p, (size_t)H * Fout * 2);
    ushort* h1     = (ushort*)bump(p, (size_t)N * H * 2);     // panel-major bf16
    float*  a1     = (float*)bump(p, (size_t)N * H * 4);      // row-major fp32
    ushort* h2     = (ushort*)bump(p, (size_t)N * Fout * 2);  // panel-major bf16

    // recs overlays a1: consumed by binD_a/b before a1 is first written.
    ull* recs = (ull*)a1;

    const int sp1 = (Fin * H + 255) / 256;      // 256
    const int sp2 = (H * Fout + 255) / 256;     // 128
    const int gb1 = (H / 128) * ((N + 127) / 128);   // GEMM1 tiles (782)
    const int pp  = (N + 255) / 256;            // permPlace blocks (196)
    int T1 = gb1 < 280 ? gb1 : 280;
    int T2 = gb1 < 480 ? gb1 : 480;
    if (T2 < T1) T2 = T1;

    // stage A: edge histogram || weight split/transpose
    k_fusedA<<<NBLK + sp1 + sp2, 256, 0, stream>>>(col, counts, E, NB,
                                                   W1, WT1h, WT1l, Fin, H,
                                                   W2, WT2h, WT2l, Fout, sp1);
    k_scanB1<<<NB, 256, 0, stream>>>(counts, btot);
    k_scanB2<<<1, 256, 0, stream>>>(btot, bbase, NB, pkhist);
    // stage B: bucket-sort || GEMM1 tiles [0,T1)
    k_fusedB1<<<NBLK + T1, 256, 0, stream>>>(row, col, ew, counts, bbase, recs, E, NB,
                                             x, WT1h, WT1l, h1, N, H, Fin, 0);
    // stage C: per-node counts/dinv/rowptr/degree-hist || GEMM1 tiles [T1,T2)
    k_fusedB2<<<NB + (T2 - T1), 256, 0, stream>>>(recs, bbase, cntp, dinv, rowptr, pkhist,
                                                  N, NB, x, WT1h, WT1l, h1, N, H, Fin, T1);
    k_permScan<<<1, 64, 0, stream>>>(pkhist, pkbase);
    // stage D: CSR emission + degree-sort placement || GEMM1 tiles [T2,gb1)
    k_fusedB3<<<NB + pp + (gb1 - T2), 256, 0, stream>>>(recs, bbase, rowptr, cntp, dinv,
                                                        edgesP, pkbase, perm, N, NB, pp,
                                                        x, WT1h, WT1l, h1, N, H, Fin, T2);

    const int chunks = (N + NPB - 1) / NPB;

    // layer 1 aggregation
    k_aggr1<<<chunks * (H / 32), 256, 0, stream>>>(perm, rowptr, cntp, edgesP, h1, dinv, b1, a1, H, H / 32, N);

    // layer 2
    k_gemm3<<<dim3(Fout / 128, (N + 127) / 128), 256, 0, stream>>>(a1, WT2h, WT2l, h2, N, Fout, H);
    k_aggr2<<<chunks * (Fout / 32), 256, 0, stream>>>(perm, rowptr, cntp, edgesP, h2, dinv, b2, out, Fout, Fout / 32, N);
}

// Round 11
// 417.788 us; speedup vs baseline: 2.1306x; 2.1306x over previous
//
#include <hip/hip_runtime.h>

typedef __attribute__((ext_vector_type(8))) short  short8;
typedef __attribute__((ext_vector_type(4))) float  f32x4;
typedef __attribute__((ext_vector_type(4))) ushort us4;
typedef __attribute__((ext_vector_type(4))) uint   u32x4;
typedef __attribute__((ext_vector_type(2))) uint   u32x2;
typedef unsigned long long ull;

__device__ __forceinline__ float bf2f(ushort u) {
    union { uint i; float f; } c; c.i = ((uint)u) << 16; return c.f;
}
__device__ __forceinline__ float bits2f(uint b) {
    union { uint i; float f; } c; c.i = b; return c.f;
}
__device__ __forceinline__ ushort f2bf(float f) {
    union { float f; uint i; } c; c.f = f;
    uint b = c.i + 0x7fffu + ((c.i >> 16) & 1u);   // RNE, no NaN inputs here
    return (ushort)(b >> 16);
}

// ================= CSR build via LDS-binned counting sort ====================
// Contiguous padded CSR. Bucket b's padded region statically starts at
// bbase[b] + 192*b (per-node x4 padding adds <= 3*64 slots per bucket), so
// binDa writes rowptr directly (no second bucket scan).
// Round-10 lesson: the degree-sort via 50K atomics onto a 64-word GLOBAL
// array serialized at the memory-side RMW units (279 us at 2% busy). The
// degree-uniform waves idea survives WITHOUT atomics: an aggr block covers
// exactly one 64-node bucket, so binDa rank-sorts nodes within its bucket in
// LDS (64x64 broadcast compares) and writes perm[b*64+rank]=node.
#define NBLK  256     // blocks for histA/binC
#define NBMAX 1024    // max buckets of 64 nodes (N <= 65472)

__device__ __forceinline__
void histA_body(const int* __restrict__ col, int* __restrict__ counts,
                int E, int NB, uint* hist) {
    for (int j = threadIdx.x; j < NB; j += 256) hist[j] = 0u;
    __syncthreads();
    for (int i = blockIdx.x * 256 + threadIdx.x; i < E; i += 256 * NBLK)
        atomicAdd(&hist[((uint)col[i]) >> 6], 1u);
    __syncthreads();
    for (int j = threadIdx.x; j < NB; j += 256)
        counts[j * NBLK + blockIdx.x] = (int)hist[j];
}

__device__ __forceinline__
void binC_body(const int* __restrict__ row, const int* __restrict__ col,
               const float* __restrict__ w,
               const int* __restrict__ counts, const int* __restrict__ bbase,
               ull* __restrict__ recs, int E, int NB, uint* cur) {
    for (int j = threadIdx.x; j < NB; j += 256)
        cur[j] = (uint)(bbase[j] + counts[j * NBLK + blockIdx.x]);
    __syncthreads();
    for (int i = blockIdx.x * 256 + threadIdx.x; i < E; i += 256 * NBLK) {
        int c = col[i], r = row[i];
        float wv = w[i];
        uint w16 = (uint)(wv * 65536.0f);
        if (w16 > 65535u) w16 = 65535u;
        uint pos = atomicAdd(&cur[((uint)c) >> 6], 1u);
        recs[pos] = ((ull)(uint)c << 32) | (ull)((w16 << 16) | (uint)(r & 0xffff));
    }
}

// per bucket: per-node count/wsum -> dinv, padded count, rowptr (static bucket
// base + local scan), and within-bucket degree-rank permutation (NO atomics).
__device__ __forceinline__
void binDa_body(const ull* __restrict__ recs, const int* __restrict__ bbase,
                int* __restrict__ cntp, float* __restrict__ dinv,
                int* __restrict__ rowptr, ushort* __restrict__ perm, int N,
                uint* cnt, uint* ws, uint* arr, uint* keys) {
    int b = blockIdx.x, t = threadIdx.x;
    if (t < 64) { cnt[t] = 0u; ws[t] = 0u; }
    __syncthreads();
    int lo = bbase[b], hi = bbase[b + 1];
    for (int i = lo + t; i < hi; i += 256) {
        ull rec = recs[i];
        atomicAdd(&cnt[((uint)(rec >> 32)) & 63u], 1u);
        atomicAdd(&ws[((uint)(rec >> 32)) & 63u], (uint)((rec >> 16) & 0xffffu));
    }
    __syncthreads();
    int node = b * 64 + t;
    uint cp = 0;
    if (t < 64) {
        if (node < N) cp = (cnt[t] + 3u) & ~3u;
        arr[t] = cp;
        keys[t] = (node < N) ? cp : 0xffffffffu;   // invalid nodes rank last
    }
    __syncthreads();
    for (int off = 1; off < 64; off <<= 1) {
        uint x = (t < 64 && t >= off) ? arr[t - off] : 0u;
        __syncthreads();
        if (t < 64) arr[t] += x;
        __syncthreads();
    }
    if (t < 64 && node < N) {
        int base = bbase[b] + 192 * b;
        rowptr[node] = base + (int)(arr[t] - cp);
        cntp[node]   = (int)cp;
        dinv[node]   = rsqrtf(1.0f + (float)ws[t] * (1.0f / 65536.0f));
        // stable within-bucket degree rank (64 broadcast compares, no atomics)
        uint key = keys[t];
        int rank = 0;
        #pragma unroll 8
        for (int j = 0; j < 64; ++j) {
            uint kj = keys[j];
            rank += (kj < key) || (kj == key && j < t);
        }
        perm[b * 64 + rank] = (ushort)node;
    }
}

// per bucket: place edges with packed bf16 norm at rowptr offsets; zero pads.
__device__ __forceinline__
void binDb_body(const ull* __restrict__ recs, const int* __restrict__ bbase,
                const int* __restrict__ rowptr, const int* __restrict__ cntp,
                const float* __restrict__ dinv, uint* __restrict__ edgesP, int N,
                uint* curN, uint* rbs, uint* cps) {
    int b = blockIdx.x, t = threadIdx.x;
    int node = b * 64 + t;
    if (t < 64) {
        uint rp = 0u, cp = 0u;
        if (node < N) { rp = (uint)rowptr[node]; cp = (uint)cntp[node]; }
        rbs[t] = rp; curN[t] = rp; cps[t] = cp;
    }
    __syncthreads();
    int lo = bbase[b], hi = bbase[b + 1];
    for (int i = lo + t; i < hi; i += 256) {
        ull rec = recs[i];
        uint c   = (uint)(rec >> 32);
        uint r   = (uint)rec & 0xffffu;
        uint w16 = ((uint)rec >> 16) & 0xffffu;
        float nv = dinv[r] * ((float)w16 * (1.0f / 65536.0f)) * dinv[c];
        uint slot = atomicAdd(&curN[c & 63u], 1u);
        edgesP[slot] = r | ((uint)f2bf(nv) << 16);
    }
    __syncthreads();
    if (t < 64 && node < N) {
        uint e1 = rbs[t] + cps[t];
        for (uint j = curN[t]; j < e1; ++j) edgesP[j] = 0u;  // nv=0, r=0 pad
    }
}

// exclusive scan of counts[b][0..255] in place; bucket totals out.
__global__ void k_scanB1(int* __restrict__ counts, int* __restrict__ btot) {
    __shared__ int s[256];
    int b = blockIdx.x, t = threadIdx.x;
    int v = counts[b * NBLK + t];
    s[t] = v; __syncthreads();
    for (int off = 1; off < 256; off <<= 1) {
        int x = (t >= off) ? s[t - off] : 0;
        __syncthreads();
        s[t] += x;
        __syncthreads();
    }
    counts[b * NBLK + t] = s[t] - v;
    if (t == 255) btot[b] = s[255];
}

// exclusive scan of up to 1023 totals -> base[0..NB].
__global__ void k_scanB2(const int* __restrict__ btot, int* __restrict__ bbase, int NB) {
    __shared__ int s[256];
    int t = threadIdx.x;
    int v[4]; int sum = 0;
    #pragma unroll
    for (int j = 0; j < 4; ++j) {
        int i = t * 4 + j;
        v[j] = (i < NB) ? btot[i] : 0;
        sum += v[j];
    }
    s[t] = sum; __syncthreads();
    for (int off = 1; off < 256; off <<= 1) {
        int x = (t >= off) ? s[t - off] : 0;
        __syncthreads();
        s[t] += x;
        __syncthreads();
    }
    int excl = s[t] - sum;
    #pragma unroll
    for (int j = 0; j < 4; ++j) {
        int i = t * 4 + j;
        if (i <= NB) bbase[i] = excl;
        excl += v[j];
    }
}

// ================= weight split + transpose: W[K][N] -> WT{h,l}[N][K] ==========
__device__ __forceinline__
void splitT_body(const float* __restrict__ W, ushort* __restrict__ Th,
                 ushort* __restrict__ Tl, int K, int N, int i) {
    if (i < K * N) {
        int k = i / N, n = i - k * N;
        float v = W[i];
        ushort hi = f2bf(v);
        ushort lo = f2bf(v - bf2f(hi));
        Th[(size_t)n * K + k] = hi;
        Tl[(size_t)n * K + k] = lo;
    }
}

// ================= MFMA GEMM core =============================================
// Tile 128x128, BK=32, 256 thr = 4 waves (2x2), wave = 64x64 = 4x4 MFMA tiles.
// 3-product split precision: Ah*Bh + Ah*Bl + Al*Bh.
#define LDA 40   // padded LDS row stride (bf16 elems); 80 B = 5*16 keeps 16B align

__device__ __forceinline__
void gemm3_body(const float* __restrict__ A, const ushort* __restrict__ BTh,
                const ushort* __restrict__ BTl, ushort* __restrict__ Cpan,
                int M, int Nc, int K, int bm, int bn,
                ushort (*As)[128][LDA], ushort (*Bs)[128][LDA]) {
    const int t    = threadIdx.x;
    const int lane = t & 63;
    const int wid  = t >> 6;
    const int wm   = wid >> 1;
    const int wn   = wid & 1;
    const int ml   = lane & 15;
    const int kq   = lane >> 4;

    f32x4 acc[4][4];
    #pragma unroll
    for (int mt = 0; mt < 4; ++mt)
        #pragma unroll
        for (int nt = 0; nt < 4; ++nt) acc[mt][nt] = (f32x4){0.f, 0.f, 0.f, 0.f};

    for (int k0 = 0; k0 < K; k0 += 32) {
        #pragma unroll
        for (int it = 0; it < 4; ++it) {
            int idx = (t + it * 256) * 4;
            int r  = idx >> 5;
            int kk = idx & 31;
            int grow = bm + r;
            f32x4 v = (f32x4){0.f, 0.f, 0.f, 0.f};
            if (grow < M) v = *(const f32x4*)&A[(size_t)grow * K + k0 + kk];
            us4 hi, lo;
            #pragma unroll
            for (int j = 0; j < 4; ++j) {
                ushort h = f2bf(v[j]);
                hi[j] = h;
                lo[j] = f2bf(v[j] - bf2f(h));
            }
            *(us4*)&As[0][r][kk] = hi;
            *(us4*)&As[1][r][kk] = lo;
        }
        #pragma unroll
        for (int it = 0; it < 2; ++it) {
            int idx = (t + it * 256) * 8;
            int n  = idx >> 5;
            int kk = idx & 31;
            u32x4 vh = *(const u32x4*)&BTh[(size_t)(bn + n) * K + k0 + kk];
            *(u32x4*)&Bs[0][n][kk] = vh;
            u32x4 vl = *(const u32x4*)&BTl[(size_t)(bn + n) * K + k0 + kk];
            *(u32x4*)&Bs[1][n][kk] = vl;
        }
        __syncthreads();

        short8 a[4][2], b[4][2];
        #pragma unroll
        for (int mt = 0; mt < 4; ++mt) {
            a[mt][0] = *(const short8*)&As[0][wm * 64 + mt * 16 + ml][kq * 8];
            a[mt][1] = *(const short8*)&As[1][wm * 64 + mt * 16 + ml][kq * 8];
        }
        #pragma unroll
        for (int nt = 0; nt < 4; ++nt) {
            b[nt][0] = *(const short8*)&Bs[0][wn * 64 + nt * 16 + ml][kq * 8];
            b[nt][1] = *(const short8*)&Bs[1][wn * 64 + nt * 16 + ml][kq * 8];
        }
        #pragma unroll
        for (int mt = 0; mt < 4; ++mt)
            #pragma unroll
            for (int nt = 0; nt < 4; ++nt) {
                acc[mt][nt] = __builtin_amdgcn_mfma_f32_16x16x32_bf16(a[mt][0], b[nt][0], acc[mt][nt], 0, 0, 0);
                acc[mt][nt] = __builtin_amdgcn_mfma_f32_16x16x32_bf16(a[mt][0], b[nt][1], acc[mt][nt], 0, 0, 0);
                acc[mt][nt] = __builtin_amdgcn_mfma_f32_16x16x32_bf16(a[mt][1], b[nt][0], acc[mt][nt], 0, 0, 0);
            }
        __syncthreads();
    }

    #pragma unroll
    for (int mt = 0; mt < 4; ++mt) {
        int rbase = bm + wm * 64 + mt * 16 + kq * 4;
        #pragma unroll
        for (int nt = 0; nt < 4; ++nt) {
            int colg = bn + wn * 64 + nt * 16 + ml;
            size_t pbase = (size_t)(colg >> 5) * M * 32 + (colg & 31);
            #pragma unroll
            for (int r = 0; r < 4; ++r) {
                int rr = rbase + r;
                if (rr < M) Cpan[pbase + (size_t)rr * 32] = f2bf(acc[mt][nt][r]);
            }
        }
    }
}

__global__ __launch_bounds__(256)
void k_gemm3(const float* __restrict__ A, const ushort* __restrict__ BTh,
             const ushort* __restrict__ BTl, ushort* __restrict__ Cpan,
             int M, int Nc, int K) {
    __shared__ __align__(16) ushort As[2][128][LDA];
    __shared__ __align__(16) ushort Bs[2][128][LDA];
    gemm3_body(A, BTh, BTl, Cpan, M, Nc, K, blockIdx.y * 128, blockIdx.x * 128, As, Bs);
}

// ================= fused launches (binning || GEMM1 tiles) ===================
__global__ __launch_bounds__(256)
void k_fusedA(const int* __restrict__ col, int* __restrict__ counts, int E, int NB,
              const float* __restrict__ W1, ushort* __restrict__ WT1h, ushort* __restrict__ WT1l,
              int Fin, int H,
              const float* __restrict__ W2, ushort* __restrict__ WT2h, ushort* __restrict__ WT2l,
              int Fout, int sp1) {
    __shared__ uint hist[NBMAX];
    int bid = (int)blockIdx.x;
    if (bid < NBLK) { histA_body(col, counts, E, NB, hist); return; }
    if (bid < NBLK + sp1) { splitT_body(W1, WT1h, WT1l, Fin, H, (bid - NBLK) * 256 + (int)threadIdx.x); return; }
    splitT_body(W2, WT2h, WT2l, H, Fout, (bid - NBLK - sp1) * 256 + (int)threadIdx.x);
}

__global__ __launch_bounds__(256)
void k_fusedB1(const int* __restrict__ row, const int* __restrict__ col,
               const float* __restrict__ w, const int* __restrict__ counts,
               const int* __restrict__ bbase, ull* __restrict__ recs, int E, int NB,
               const float* __restrict__ A, const ushort* __restrict__ BTh,
               const ushort* __restrict__ BTl, ushort* __restrict__ Cpan,
               int M, int Nc, int K, int t0) {
    __shared__ __align__(16) ushort As[2][128][LDA];
    __shared__ __align__(16) ushort Bs[2][128][LDA];
    int bid = (int)blockIdx.x;
    if (bid < NBLK) { binC_body(row, col, w, counts, bbase, recs, E, NB, (uint*)&As[0][0][0]); return; }
    int tile = t0 + bid - NBLK;
    int nbn = Nc >> 7;
    gemm3_body(A, BTh, BTl, Cpan, M, Nc, K, (tile / nbn) * 128, (tile % nbn) * 128, As, Bs);
}

__global__ __launch_bounds__(256)
void k_fusedB2(const ull* __restrict__ recs, const int* __restrict__ bbase,
               int* __restrict__ cntp, float* __restrict__ dinv,
               int* __restrict__ rowptr, ushort* __restrict__ perm,
               int N, int NB,
               const float* __restrict__ A, const ushort* __restrict__ BTh,
               const ushort* __restrict__ BTl, ushort* __restrict__ Cpan,
               int M, int Nc, int K, int t0) {
    __shared__ __align__(16) ushort As[2][128][LDA];
    __shared__ __align__(16) ushort Bs[2][128][LDA];
    int bid = (int)blockIdx.x;
    if (bid < NB) {
        uint* l = (uint*)&As[0][0][0];
        binDa_body(recs, bbase, cntp, dinv, rowptr, perm, N, l, l + 64, l + 128, l + 192);
        return;
    }
    int tile = t0 + bid - NB;
    int nbn = Nc >> 7;
    gemm3_body(A, BTh, BTl, Cpan, M, Nc, K, (tile / nbn) * 128, (tile % nbn) * 128, As, Bs);
}

__global__ __launch_bounds__(256)
void k_fusedB3(const ull* __restrict__ recs, const int* __restrict__ bbase,
               const int* __restrict__ rowptr, const int* __restrict__ cntp,
               const float* __restrict__ dinv, uint* __restrict__ edgesP,
               int N, int NB,
               const float* __restrict__ A, const ushort* __restrict__ BTh,
               const ushort* __restrict__ BTl, ushort* __restrict__ Cpan,
               int M, int Nc, int K, int t0) {
    __shared__ __align__(16) ushort As[2][128][LDA];
    __shared__ __align__(16) ushort Bs[2][128][LDA];
    int bid = (int)blockIdx.x;
    if (bid < NB) {
        uint* l = (uint*)&As[0][0][0];
        binDb_body(recs, bbase, rowptr, cntp, dinv, edgesP, N, l, l + 64, l + 128);
        return;
    }
    int tile = t0 + bid - NB;
    int nbn = Nc >> 7;
    gemm3_body(A, BTh, BTl, Cpan, M, Nc, K, (tile / nbn) * 128, (tile % nbn) * 128, As, Bs);
}

// ================= panel CSR aggregation, butterfly-free =====================
// Panel-per-block (p = bid % npan): consecutive blocks round-robin XCDs so each
// XCD's L2 holds ONE 3.2 MB panel. Lanes: g=lane>>2 (16 nodes/wave), c=lane&3
// (8 feats/lane, one 16B dwordx4 gather; 4 lanes cover one 64B row).
// A block's 64 idx slots = exactly one degree-rank-sorted bucket, so each
// wave's 16 nodes are degree-adjacent order statistics (trip ~ mean, not max).
#define NPB 64   // nodes per block: 4 waves x 16 nodes

template <bool RELU>
__device__ __forceinline__
void aggr_body(const ushort* __restrict__ perm, const int* __restrict__ rowptr,
               const int* __restrict__ cntp, const uint* __restrict__ edges,
               const ushort* __restrict__ hpan, const float* __restrict__ dinv,
               const float* __restrict__ bias, float* __restrict__ out,
               int F, int npan, int N) {
    const int bid  = blockIdx.x;
    const int p    = bid % npan;
    const int wave = threadIdx.x >> 6;
    const int lane = threadIdx.x & 63;
    const int g    = lane >> 2;        // node slot within wave (0..15)
    const int c    = lane & 3;         // feature octet within panel (0..3)
    const int idx  = (bid / npan) * NPB + wave * 16 + g;
    const int fbase = p * 32 + c * 8;

    const ushort* hp = hpan + (size_t)p * N * 32 + c * 8;   // + r*32 per gather

    int node = 0, beg = 0, end = 0;
    if (idx < N) {
        node = (int)perm[idx];
        beg = rowptr[node];
        end = beg + cntp[node];
    }

    float acc[8] = {};
    int e = beg;
    u32x4 pk4 = (u32x4){0u, 0u, 0u, 0u};
    if (e < end) pk4 = *(const u32x4*)&edges[e];
    while (__any(e < end)) {
        u32x4 cur = pk4;
        int e2 = e + 4;
        if (e2 < end) pk4 = *(const u32x4*)&edges[e2];   // prefetch next packet
        if (e < end) {
            #pragma unroll
            for (int j = 0; j < 4; ++j) {
                uint pk = cur[j];
                float nv = bits2f(pk & 0xffff0000u);
                int r = (int)(pk & 0xffffu);
                u32x4 hv = *(const u32x4*)(hp + (size_t)r * 32);
                #pragma unroll
                for (int q = 0; q < 4; ++q) {
                    acc[2 * q]     += nv * bits2f(hv[q] << 16);
                    acc[2 * q + 1] += nv * bits2f(hv[q] & 0xffff0000u);
                }
            }
        }
        e = e2;
    }

    if (idx < N) {
        float di = dinv[node];
        float d2 = di * di;
        u32x4 hs = *(const u32x4*)(hp + (size_t)node * 32);
        f32x4 bv0 = *(const f32x4*)&bias[fbase];
        f32x4 bv1 = *(const f32x4*)&bias[fbase + 4];
        f32x4 v0, v1;
        #pragma unroll
        for (int q = 0; q < 4; ++q) {
            float r0 = acc[2 * q]     + d2 * bits2f(hs[q] << 16)
                     + ((q < 2) ? bv0[2 * q] : bv1[2 * q - 4]);
            float r1 = acc[2 * q + 1] + d2 * bits2f(hs[q] & 0xffff0000u)
                     + ((q < 2) ? bv0[2 * q + 1] : bv1[2 * q - 3]);
            if (RELU) { r0 = fmaxf(r0, 0.f); r1 = fmaxf(r1, 0.f); }
            if (q < 2) { v0[2 * q] = r0; v0[2 * q + 1] = r1; }
            else       { v1[2 * q - 4] = r0; v1[2 * q - 3] = r1; }
        }
        *(f32x4*)&out[(size_t)node * F + fbase]     = v0;
        *(f32x4*)&out[(size_t)node * F + fbase + 4] = v1;
    }
}

__global__ __launch_bounds__(256)
void k_aggr1(const ushort* __restrict__ perm, const int* __restrict__ rowptr,
             const int* __restrict__ cntp, const uint* __restrict__ edges,
             const ushort* __restrict__ hpan, const float* __restrict__ dinv,
             const float* __restrict__ bias, float* __restrict__ out,
             int F, int npan, int N) {
    aggr_body<true>(perm, rowptr, cntp, edges, hpan, dinv, bias, out, F, npan, N);
}

__global__ __launch_bounds__(256)
void k_aggr2(const ushort* __restrict__ perm, const int* __restrict__ rowptr,
             const int* __restrict__ cntp, const uint* __restrict__ edges,
             const ushort* __restrict__ hpan, const float* __restrict__ dinv,
             const float* __restrict__ bias, float* __restrict__ out,
             int F, int npan, int N) {
    aggr_body<false>(perm, rowptr, cntp, edges, hpan, dinv, bias, out, F, npan, N);
}

// ================= launcher =================

static inline char* bump(char*& p, size_t bytes) {
    char* r = p;
    p += (bytes + 255) & ~(size_t)255;
    return r;
}

extern "C" void kernel_launch(void* const* d_in, const int* in_sizes, int n_in,
                              void* d_out, int out_size, void* d_ws, size_t ws_size,
                              hipStream_t stream) {
    const float* x  = (const float*)d_in[0];
    const int*   ei = (const int*)d_in[1];
    const float* ew = (const float*)d_in[2];
    const float* W1 = (const float*)d_in[3];
    const float* b1 = (const float*)d_in[4];
    const float* W2 = (const float*)d_in[5];
    const float* b2 = (const float*)d_in[6];
    float* out = (float*)d_out;

    const int E    = in_sizes[2];
    const int H    = in_sizes[4];       // 256
    const int Fout = in_sizes[6];       // 128
    const int Fin  = in_sizes[3] / H;   // 256
    const int N    = in_sizes[0] / Fin; // 50000 (fits ushort)
    const int NB   = (N + 63) >> 6;     // buckets of 64 nodes (<= 1023)

    const int* row = ei;
    const int* col = ei + E;

    char* p = (char*)d_ws;
    float*  dinv   = (float*)bump(p, (size_t)N * 4);
    int*    cntp   = (int*)bump(p, (size_t)N * 4);
    int*    rowptr = (int*)bump(p, (size_t)N * 4);
    ushort* perm   = (ushort*)bump(p, (size_t)NBMAX * 64 * 2);
    uint*   edgesP = (uint*)bump(p, ((size_t)E + 3 * N + 192 * (size_t)NBMAX + 256) * 4);
    int*    counts = (int*)bump(p, (size_t)NBMAX * NBLK * 4);
    int*    btot   = (int*)bump(p, (size_t)NBMAX * 4);
    int*    bbase  = (int*)bump(p, (size_t)(NBMAX + 1) * 4);
    ushort* WT1h   = (ushort*)bump(p, (size_t)Fin * H * 2);
    ushort* WT1l   = (ushort*)bump(p, (size_t)Fin * H * 2);
    ushort* WT2h   = (ushort*)bump(p, (size_t)H * Fout * 2);
    ushort* WT2l   = (ushort*)bump(p, (size_t)H * Fout * 2);
    ushort* h1     = (ushort*)bump(p, (size_t)N * H * 2);     // panel-major bf16
    float*  a1     = (float*)bump(p, (size_t)N * H * 4);      // row-major fp32
    ushort* h2     = (ushort*)bump(p, (size_t)N * Fout * 2);  // panel-major bf16

    // recs overlays a1: consumed by binD_a/b before a1 is first written.
    ull* recs = (ull*)a1;

    const int sp1 = (Fin * H + 255) / 256;      // 256
    const int sp2 = (H * Fout + 255) / 256;     // 128
    const int gb1 = (H / 128) * ((N + 127) / 128);   // GEMM1 tiles (782)
    int T1 = gb1 < 280 ? gb1 : 280;
    int T2 = gb1 < 480 ? gb1 : 480;
    if (T2 < T1) T2 = T1;

    // stage A: edge histogram || weight split/transpose
    k_fusedA<<<NBLK + sp1 + sp2, 256, 0, stream>>>(col, counts, E, NB,
                                                   W1, WT1h, WT1l, Fin, H,
                                                   W2, WT2h, WT2l, Fout, sp1);
    k_scanB1<<<NB, 256, 0, stream>>>(counts, btot);
    k_scanB2<<<1, 256, 0, stream>>>(btot, bbase, NB);
    // stage B: bucket-sort || GEMM1 tiles [0,T1)
    k_fusedB1<<<NBLK + T1, 256, 0, stream>>>(row, col, ew, counts, bbase, recs, E, NB,
                                             x, WT1h, WT1l, h1, N, H, Fin, 0);
    // stage C: per-node counts/dinv/rowptr/rank-perm || GEMM1 tiles [T1,T2)
    k_fusedB2<<<NB + (T2 - T1), 256, 0, stream>>>(recs, bbase, cntp, dinv, rowptr, perm,
                                                  N, NB, x, WT1h, WT1l, h1, N, H, Fin, T1);
    // stage D: CSR emission || GEMM1 tiles [T2,gb1)
    k_fusedB3<<<NB + (gb1 - T2), 256, 0, stream>>>(recs, bbase, rowptr, cntp, dinv,
                                                   edgesP, N, NB,
                                                   x, WT1h, WT1l, h1, N, H, Fin, T2);

    const int chunks = (N + NPB - 1) / NPB;

    // layer 1 aggregation
    k_aggr1<<<chunks * (H / 32), 256, 0, stream>>>(perm, rowptr, cntp, edgesP, h1, dinv, b1, a1, H, H / 32, N);

    // layer 2
    k_gemm3<<<dim3(Fout / 128, (N + 127) / 128), 256, 0, stream>>>(a1, WT2h, WT2l, h2, N, Fout, H);
    k_aggr2<<<chunks * (Fout / 32), 256, 0, stream>>>(perm, rowptr, cntp, edgesP, h2, dinv, b2, out, Fout, Fout / 32, N);
}

// Round 12
// 408.919 us; speedup vs baseline: 2.1768x; 1.0217x over previous
//
#include <hip/hip_runtime.h>

typedef __attribute__((ext_vector_type(8))) short  short8;
typedef __attribute__((ext_vector_type(4))) float  f32x4;
typedef __attribute__((ext_vector_type(4))) ushort us4;
typedef __attribute__((ext_vector_type(4))) uint   u32x4;
typedef __attribute__((ext_vector_type(2))) uint   u32x2;
typedef unsigned long long ull;

__device__ __forceinline__ float bf2f(ushort u) {
    union { uint i; float f; } c; c.i = ((uint)u) << 16; return c.f;
}
__device__ __forceinline__ float bits2f(uint b) {
    union { uint i; float f; } c; c.i = b; return c.f;
}
__device__ __forceinline__ ushort f2bf(float f) {
    union { float f; uint i; } c; c.f = f;
    uint b = c.i + 0x7fffu + ((c.i >> 16) & 1u);   // RNE, no NaN inputs here
    return (ushort)(b >> 16);
}

// ================= CSR build via LDS-binned counting sort ====================
// Contiguous padded CSR. Bucket b's padded region statically starts at
// bbase[b] + 192*b (per-node x4 padding adds <= 3*64 slots per bucket), so
// binDa writes rowptr directly (no second bucket scan). binDa also rank-sorts
// nodes within its bucket in LDS (no global atomics — round-10 lesson: 50K
// atomics onto 64 global words serialized at the memory-side RMW units).
#define NBLK  256     // blocks for histA/binC
#define NBMAX 1024    // max buckets of 64 nodes (N <= 65472)

__device__ __forceinline__
void histA_body(const int* __restrict__ col, int* __restrict__ counts,
                int E, int NB, uint* hist) {
    for (int j = threadIdx.x; j < NB; j += 256) hist[j] = 0u;
    __syncthreads();
    for (int i = blockIdx.x * 256 + threadIdx.x; i < E; i += 256 * NBLK)
        atomicAdd(&hist[((uint)col[i]) >> 6], 1u);
    __syncthreads();
    for (int j = threadIdx.x; j < NB; j += 256)
        counts[j * NBLK + blockIdx.x] = (int)hist[j];
}

__device__ __forceinline__
void binC_body(const int* __restrict__ row, const int* __restrict__ col,
               const float* __restrict__ w,
               const int* __restrict__ counts, const int* __restrict__ bbase,
               ull* __restrict__ recs, int E, int NB, uint* cur) {
    for (int j = threadIdx.x; j < NB; j += 256)
        cur[j] = (uint)(bbase[j] + counts[j * NBLK + blockIdx.x]);
    __syncthreads();
    for (int i = blockIdx.x * 256 + threadIdx.x; i < E; i += 256 * NBLK) {
        int c = col[i], r = row[i];
        float wv = w[i];
        uint w16 = (uint)(wv * 65536.0f);
        if (w16 > 65535u) w16 = 65535u;
        uint pos = atomicAdd(&cur[((uint)c) >> 6], 1u);
        recs[pos] = ((ull)(uint)c << 32) | (ull)((w16 << 16) | (uint)(r & 0xffff));
    }
}

// per bucket: per-node count/wsum -> dinv, padded count, rowptr (static bucket
// base + local scan), and within-bucket degree-rank permutation (NO atomics).
__device__ __forceinline__
void binDa_body(const ull* __restrict__ recs, const int* __restrict__ bbase,
                int* __restrict__ cntp, float* __restrict__ dinv,
                int* __restrict__ rowptr, ushort* __restrict__ perm, int N,
                uint* cnt, uint* ws, uint* arr, uint* keys) {
    int b = blockIdx.x, t = threadIdx.x;
    if (t < 64) { cnt[t] = 0u; ws[t] = 0u; }
    __syncthreads();
    int lo = bbase[b], hi = bbase[b + 1];
    for (int i = lo + t; i < hi; i += 256) {
        ull rec = recs[i];
        atomicAdd(&cnt[((uint)(rec >> 32)) & 63u], 1u);
        atomicAdd(&ws[((uint)(rec >> 32)) & 63u], (uint)((rec >> 16) & 0xffffu));
    }
    __syncthreads();
    int node = b * 64 + t;
    uint cp = 0;
    if (t < 64) {
        if (node < N) cp = (cnt[t] + 3u) & ~3u;
        arr[t] = cp;
        keys[t] = (node < N) ? cp : 0xffffffffu;   // invalid nodes rank last
    }
    __syncthreads();
    for (int off = 1; off < 64; off <<= 1) {
        uint x = (t < 64 && t >= off) ? arr[t - off] : 0u;
        __syncthreads();
        if (t < 64) arr[t] += x;
        __syncthreads();
    }
    if (t < 64 && node < N) {
        int base = bbase[b] + 192 * b;
        rowptr[node] = base + (int)(arr[t] - cp);
        cntp[node]   = (int)cp;
        dinv[node]   = rsqrtf(1.0f + (float)ws[t] * (1.0f / 65536.0f));
        // stable within-bucket degree rank (64 broadcast compares, no atomics)
        uint key = keys[t];
        int rank = 0;
        #pragma unroll 8
        for (int j = 0; j < 64; ++j) {
            uint kj = keys[j];
            rank += (kj < key) || (kj == key && j < t);
        }
        perm[b * 64 + rank] = (ushort)node;
    }
}

// per bucket: place edges with packed bf16 norm at rowptr offsets; zero pads.
__device__ __forceinline__
void binDb_body(const ull* __restrict__ recs, const int* __restrict__ bbase,
                const int* __restrict__ rowptr, const int* __restrict__ cntp,
                const float* __restrict__ dinv, uint* __restrict__ edgesP, int N,
                uint* curN, uint* rbs, uint* cps) {
    int b = blockIdx.x, t = threadIdx.x;
    int node = b * 64 + t;
    if (t < 64) {
        uint rp = 0u, cp = 0u;
        if (node < N) { rp = (uint)rowptr[node]; cp = (uint)cntp[node]; }
        rbs[t] = rp; curN[t] = rp; cps[t] = cp;
    }
    __syncthreads();
    int lo = bbase[b], hi = bbase[b + 1];
    for (int i = lo + t; i < hi; i += 256) {
        ull rec = recs[i];
        uint c   = (uint)(rec >> 32);
        uint r   = (uint)rec & 0xffffu;
        uint w16 = ((uint)rec >> 16) & 0xffffu;
        float nv = dinv[r] * ((float)w16 * (1.0f / 65536.0f)) * dinv[c];
        uint slot = atomicAdd(&curN[c & 63u], 1u);
        edgesP[slot] = r | ((uint)f2bf(nv) << 16);
    }
    __syncthreads();
    if (t < 64 && node < N) {
        uint e1 = rbs[t] + cps[t];
        for (uint j = curN[t]; j < e1; ++j) edgesP[j] = 0u;  // nv=0, r=0 pad
    }
}

// exclusive scan of counts[b][0..255] in place; bucket totals out.
__global__ void k_scanB1(int* __restrict__ counts, int* __restrict__ btot) {
    __shared__ int s[256];
    int b = blockIdx.x, t = threadIdx.x;
    int v = counts[b * NBLK + t];
    s[t] = v; __syncthreads();
    for (int off = 1; off < 256; off <<= 1) {
        int x = (t >= off) ? s[t - off] : 0;
        __syncthreads();
        s[t] += x;
        __syncthreads();
    }
    counts[b * NBLK + t] = s[t] - v;
    if (t == 255) btot[b] = s[255];
}

// exclusive scan of up to 1023 totals -> base[0..NB].
__global__ void k_scanB2(const int* __restrict__ btot, int* __restrict__ bbase, int NB) {
    __shared__ int s[256];
    int t = threadIdx.x;
    int v[4]; int sum = 0;
    #pragma unroll
    for (int j = 0; j < 4; ++j) {
        int i = t * 4 + j;
        v[j] = (i < NB) ? btot[i] : 0;
        sum += v[j];
    }
    s[t] = sum; __syncthreads();
    for (int off = 1; off < 256; off <<= 1) {
        int x = (t >= off) ? s[t - off] : 0;
        __syncthreads();
        s[t] += x;
        __syncthreads();
    }
    int excl = s[t] - sum;
    #pragma unroll
    for (int j = 0; j < 4; ++j) {
        int i = t * 4 + j;
        if (i <= NB) bbase[i] = excl;
        excl += v[j];
    }
}

// ================= weight split + transpose: W[K][N] -> WT{h,l}[N][K] ==========
__device__ __forceinline__
void splitT_body(const float* __restrict__ W, ushort* __restrict__ Th,
                 ushort* __restrict__ Tl, int K, int N, int i) {
    if (i < K * N) {
        int k = i / N, n = i - k * N;
        float v = W[i];
        ushort hi = f2bf(v);
        ushort lo = f2bf(v - bf2f(hi));
        Th[(size_t)n * K + k] = hi;
        Tl[(size_t)n * K + k] = lo;
    }
}

// ================= MFMA GEMM core =============================================
// Tile 128x128, BK=32, 256 thr = 4 waves (2x2), wave = 64x64 = 4x4 MFMA tiles.
// 3-product split precision: Ah*Bh + Ah*Bl + Al*Bh.
#define LDA 40   // padded LDS row stride (bf16 elems); 80 B = 5*16 keeps 16B align

__device__ __forceinline__
void gemm3_body(const float* __restrict__ A, const ushort* __restrict__ BTh,
                const ushort* __restrict__ BTl, ushort* __restrict__ Cpan,
                int M, int Nc, int K, int bm, int bn,
                ushort (*As)[128][LDA], ushort (*Bs)[128][LDA]) {
    const int t    = threadIdx.x;
    const int lane = t & 63;
    const int wid  = t >> 6;
    const int wm   = wid >> 1;
    const int wn   = wid & 1;
    const int ml   = lane & 15;
    const int kq   = lane >> 4;

    f32x4 acc[4][4];
    #pragma unroll
    for (int mt = 0; mt < 4; ++mt)
        #pragma unroll
        for (int nt = 0; nt < 4; ++nt) acc[mt][nt] = (f32x4){0.f, 0.f, 0.f, 0.f};

    for (int k0 = 0; k0 < K; k0 += 32) {
        #pragma unroll
        for (int it = 0; it < 4; ++it) {
            int idx = (t + it * 256) * 4;
            int r  = idx >> 5;
            int kk = idx & 31;
            int grow = bm + r;
            f32x4 v = (f32x4){0.f, 0.f, 0.f, 0.f};
            if (grow < M) v = *(const f32x4*)&A[(size_t)grow * K + k0 + kk];
            us4 hi, lo;
            #pragma unroll
            for (int j = 0; j < 4; ++j) {
                ushort h = f2bf(v[j]);
                hi[j] = h;
                lo[j] = f2bf(v[j] - bf2f(h));
            }
            *(us4*)&As[0][r][kk] = hi;
            *(us4*)&As[1][r][kk] = lo;
        }
        #pragma unroll
        for (int it = 0; it < 2; ++it) {
            int idx = (t + it * 256) * 8;
            int n  = idx >> 5;
            int kk = idx & 31;
            u32x4 vh = *(const u32x4*)&BTh[(size_t)(bn + n) * K + k0 + kk];
            *(u32x4*)&Bs[0][n][kk] = vh;
            u32x4 vl = *(const u32x4*)&BTl[(size_t)(bn + n) * K + k0 + kk];
            *(u32x4*)&Bs[1][n][kk] = vl;
        }
        __syncthreads();

        short8 a[4][2], b[4][2];
        #pragma unroll
        for (int mt = 0; mt < 4; ++mt) {
            a[mt][0] = *(const short8*)&As[0][wm * 64 + mt * 16 + ml][kq * 8];
            a[mt][1] = *(const short8*)&As[1][wm * 64 + mt * 16 + ml][kq * 8];
        }
        #pragma unroll
        for (int nt = 0; nt < 4; ++nt) {
            b[nt][0] = *(const short8*)&Bs[0][wn * 64 + nt * 16 + ml][kq * 8];
            b[nt][1] = *(const short8*)&Bs[1][wn * 64 + nt * 16 + ml][kq * 8];
        }
        #pragma unroll
        for (int mt = 0; mt < 4; ++mt)
            #pragma unroll
            for (int nt = 0; nt < 4; ++nt) {
                acc[mt][nt] = __builtin_amdgcn_mfma_f32_16x16x32_bf16(a[mt][0], b[nt][0], acc[mt][nt], 0, 0, 0);
                acc[mt][nt] = __builtin_amdgcn_mfma_f32_16x16x32_bf16(a[mt][0], b[nt][1], acc[mt][nt], 0, 0, 0);
                acc[mt][nt] = __builtin_amdgcn_mfma_f32_16x16x32_bf16(a[mt][1], b[nt][0], acc[mt][nt], 0, 0, 0);
            }
        __syncthreads();
    }

    #pragma unroll
    for (int mt = 0; mt < 4; ++mt) {
        int rbase = bm + wm * 64 + mt * 16 + kq * 4;
        #pragma unroll
        for (int nt = 0; nt < 4; ++nt) {
            int colg = bn + wn * 64 + nt * 16 + ml;
            size_t pbase = (size_t)(colg >> 5) * M * 32 + (colg & 31);
            #pragma unroll
            for (int r = 0; r < 4; ++r) {
                int rr = rbase + r;
                if (rr < M) Cpan[pbase + (size_t)rr * 32] = f2bf(acc[mt][nt][r]);
            }
        }
    }
}

__global__ __launch_bounds__(256)
void k_gemm3(const float* __restrict__ A, const ushort* __restrict__ BTh,
             const ushort* __restrict__ BTl, ushort* __restrict__ Cpan,
             int M, int Nc, int K) {
    __shared__ __align__(16) ushort As[2][128][LDA];
    __shared__ __align__(16) ushort Bs[2][128][LDA];
    gemm3_body(A, BTh, BTl, Cpan, M, Nc, K, blockIdx.y * 128, blockIdx.x * 128, As, Bs);
}

// ================= fused launches (binning || GEMM1 tiles) ===================
__global__ __launch_bounds__(256)
void k_fusedA(const int* __restrict__ col, int* __restrict__ counts, int E, int NB,
              const float* __restrict__ W1, ushort* __restrict__ WT1h, ushort* __restrict__ WT1l,
              int Fin, int H,
              const float* __restrict__ W2, ushort* __restrict__ WT2h, ushort* __restrict__ WT2l,
              int Fout, int sp1) {
    __shared__ uint hist[NBMAX];
    int bid = (int)blockIdx.x;
    if (bid < NBLK) { histA_body(col, counts, E, NB, hist); return; }
    if (bid < NBLK + sp1) { splitT_body(W1, WT1h, WT1l, Fin, H, (bid - NBLK) * 256 + (int)threadIdx.x); return; }
    splitT_body(W2, WT2h, WT2l, H, Fout, (bid - NBLK - sp1) * 256 + (int)threadIdx.x);
}

__global__ __launch_bounds__(256)
void k_fusedB1(const int* __restrict__ row, const int* __restrict__ col,
               const float* __restrict__ w, const int* __restrict__ counts,
               const int* __restrict__ bbase, ull* __restrict__ recs, int E, int NB,
               const float* __restrict__ A, const ushort* __restrict__ BTh,
               const ushort* __restrict__ BTl, ushort* __restrict__ Cpan,
               int M, int Nc, int K, int t0) {
    __shared__ __align__(16) ushort As[2][128][LDA];
    __shared__ __align__(16) ushort Bs[2][128][LDA];
    int bid = (int)blockIdx.x;
    if (bid < NBLK) { binC_body(row, col, w, counts, bbase, recs, E, NB, (uint*)&As[0][0][0]); return; }
    int tile = t0 + bid - NBLK;
    int nbn = Nc >> 7;
    gemm3_body(A, BTh, BTl, Cpan, M, Nc, K, (tile / nbn) * 128, (tile % nbn) * 128, As, Bs);
}

__global__ __launch_bounds__(256)
void k_fusedB2(const ull* __restrict__ recs, const int* __restrict__ bbase,
               int* __restrict__ cntp, float* __restrict__ dinv,
               int* __restrict__ rowptr, ushort* __restrict__ perm,
               int N, int NB,
               const float* __restrict__ A, const ushort* __restrict__ BTh,
               const ushort* __restrict__ BTl, ushort* __restrict__ Cpan,
               int M, int Nc, int K, int t0) {
    __shared__ __align__(16) ushort As[2][128][LDA];
    __shared__ __align__(16) ushort Bs[2][128][LDA];
    int bid = (int)blockIdx.x;
    if (bid < NB) {
        uint* l = (uint*)&As[0][0][0];
        binDa_body(recs, bbase, cntp, dinv, rowptr, perm, N, l, l + 64, l + 128, l + 192);
        return;
    }
    int tile = t0 + bid - NB;
    int nbn = Nc >> 7;
    gemm3_body(A, BTh, BTl, Cpan, M, Nc, K, (tile / nbn) * 128, (tile % nbn) * 128, As, Bs);
}

__global__ __launch_bounds__(256)
void k_fusedB3(const ull* __restrict__ recs, const int* __restrict__ bbase,
               const int* __restrict__ rowptr, const int* __restrict__ cntp,
               const float* __restrict__ dinv, uint* __restrict__ edgesP,
               int N, int NB,
               const float* __restrict__ A, const ushort* __restrict__ BTh,
               const ushort* __restrict__ BTl, ushort* __restrict__ Cpan,
               int M, int Nc, int K, int t0) {
    __shared__ __align__(16) ushort As[2][128][LDA];
    __shared__ __align__(16) ushort Bs[2][128][LDA];
    int bid = (int)blockIdx.x;
    if (bid < NB) {
        uint* l = (uint*)&As[0][0][0];
        binDb_body(recs, bbase, rowptr, cntp, dinv, edgesP, N, l, l + 64, l + 128);
        return;
    }
    int tile = t0 + bid - NB;
    int nbn = Nc >> 7;
    gemm3_body(A, BTh, BTl, Cpan, M, Nc, K, (tile / nbn) * 128, (tile % nbn) * 128, As, Bs);
}

// ================= panel CSR aggregation, butterfly-free =====================
// Panel-per-block (p = bid % npan): consecutive blocks round-robin XCDs so each
// XCD's L2 holds ONE 3.2 MB panel. Lanes: g=lane>>2 (16 nodes/wave), c=lane&3
// (8 feats/lane, one 16B dwordx4 gather; 4 lanes cover one 64B row).
// Round-11 lesson: flat 25-40% on every pipe = dependent-latency-bound. The
// gather->FMA chain is now 2-deep software-pipelined: trip B's gathers issue
// BEFORE trip A's FMAs consume (gathers mature across a full iteration; 8
// gathers in flight per thread instead of 4). Pad packets are zero (r=0,
// nv=+0) so pipelined gathers past the segment end are harmless row-0 reads.
#define NPB 64   // nodes per block: 4 waves x 16 nodes

template <bool RELU>
__device__ __forceinline__
void aggr_body(const ushort* __restrict__ perm, const int* __restrict__ rowptr,
               const int* __restrict__ cntp, const uint* __restrict__ edges,
               const ushort* __restrict__ hpan, const float* __restrict__ dinv,
               const float* __restrict__ bias, float* __restrict__ out,
               int F, int npan, int N) {
    const int bid  = blockIdx.x;
    const int p    = bid % npan;
    const int wave = threadIdx.x >> 6;
    const int lane = threadIdx.x & 63;
    const int g    = lane >> 2;        // node slot within wave (0..15)
    const int c    = lane & 3;         // feature octet within panel (0..3)
    const int idx  = (bid / npan) * NPB + wave * 16 + g;
    const int fbase = p * 32 + c * 8;

    const ushort* hp = hpan + (size_t)p * N * 32 + c * 8;   // + r*32 per gather

    int node = 0, beg = 0, end = 0;
    if (idx < N) {
        node = (int)perm[idx];
        beg = rowptr[node];
        end = beg + cntp[node];
    }

    float acc[8] = {};
    int e0 = beg;
    int e1 = beg + 4;
    u32x4 pkA = (u32x4){0u, 0u, 0u, 0u};
    u32x4 pkB = (u32x4){0u, 0u, 0u, 0u};
    if (e0 < end) pkA = *(const u32x4*)&edges[e0];
    if (e1 < end) pkB = *(const u32x4*)&edges[e1];
    // issue trip-A gathers (r=0 for invalid slots -> harmless row-0 read)
    u32x4 hvA0 = *(const u32x4*)(hp + (size_t)(pkA[0] & 0xffffu) * 32);
    u32x4 hvA1 = *(const u32x4*)(hp + (size_t)(pkA[1] & 0xffffu) * 32);
    u32x4 hvA2 = *(const u32x4*)(hp + (size_t)(pkA[2] & 0xffffu) * 32);
    u32x4 hvA3 = *(const u32x4*)(hp + (size_t)(pkA[3] & 0xffffu) * 32);

    while (__any(e0 < end)) {
        // prefetch packet C (two trips ahead)
        int e2 = e1 + 4;
        u32x4 pkC = (u32x4){0u, 0u, 0u, 0u};
        if (e2 < end) pkC = *(const u32x4*)&edges[e2];
        // issue trip-B gathers before consuming trip A
        u32x4 hvB0 = *(const u32x4*)(hp + (size_t)(pkB[0] & 0xffffu) * 32);
        u32x4 hvB1 = *(const u32x4*)(hp + (size_t)(pkB[1] & 0xffffu) * 32);
        u32x4 hvB2 = *(const u32x4*)(hp + (size_t)(pkB[2] & 0xffffu) * 32);
        u32x4 hvB3 = *(const u32x4*)(hp + (size_t)(pkB[3] & 0xffffu) * 32);
        // consume trip A (nv=0 for pad slots -> adds zero)
        if (e0 < end) {
            {
                float nv = bits2f(pkA[0] & 0xffff0000u);
                #pragma unroll
                for (int q = 0; q < 4; ++q) {
                    acc[2 * q]     += nv * bits2f(hvA0[q] << 16);
                    acc[2 * q + 1] += nv * bits2f(hvA0[q] & 0xffff0000u);
                }
            }
            {
                float nv = bits2f(pkA[1] & 0xffff0000u);
                #pragma unroll
                for (int q = 0; q < 4; ++q) {
                    acc[2 * q]     += nv * bits2f(hvA1[q] << 16);
                    acc[2 * q + 1] += nv * bits2f(hvA1[q] & 0xffff0000u);
                }
            }
            {
                float nv = bits2f(pkA[2] & 0xffff0000u);
                #pragma unroll
                for (int q = 0; q < 4; ++q) {
                    acc[2 * q]     += nv * bits2f(hvA2[q] << 16);
                    acc[2 * q + 1] += nv * bits2f(hvA2[q] & 0xffff0000u);
                }
            }
            {
                float nv = bits2f(pkA[3] & 0xffff0000u);
                #pragma unroll
                for (int q = 0; q < 4; ++q) {
                    acc[2 * q]     += nv * bits2f(hvA3[q] << 16);
                    acc[2 * q + 1] += nv * bits2f(hvA3[q] & 0xffff0000u);
                }
            }
        }
        // rotate pipeline registers (all named — no runtime indexing)
        pkA = pkB; pkB = pkC;
        hvA0 = hvB0; hvA1 = hvB1; hvA2 = hvB2; hvA3 = hvB3;
        e0 = e1; e1 = e2;
    }

    if (idx < N) {
        float di = dinv[node];
        float d2 = di * di;
        u32x4 hs = *(const u32x4*)(hp + (size_t)node * 32);
        f32x4 bv0 = *(const f32x4*)&bias[fbase];
        f32x4 bv1 = *(const f32x4*)&bias[fbase + 4];
        f32x4 v0, v1;
        #pragma unroll
        for (int q = 0; q < 4; ++q) {
            float r0 = acc[2 * q]     + d2 * bits2f(hs[q] << 16)
                     + ((q < 2) ? bv0[2 * q] : bv1[2 * q - 4]);
            float r1 = acc[2 * q + 1] + d2 * bits2f(hs[q] & 0xffff0000u)
                     + ((q < 2) ? bv0[2 * q + 1] : bv1[2 * q - 3]);
            if (RELU) { r0 = fmaxf(r0, 0.f); r1 = fmaxf(r1, 0.f); }
            if (q < 2) { v0[2 * q] = r0; v0[2 * q + 1] = r1; }
            else       { v1[2 * q - 4] = r0; v1[2 * q - 3] = r1; }
        }
        *(f32x4*)&out[(size_t)node * F + fbase]     = v0;
        *(f32x4*)&out[(size_t)node * F + fbase + 4] = v1;
    }
}

__global__ __launch_bounds__(256)
void k_aggr1(const ushort* __restrict__ perm, const int* __restrict__ rowptr,
             const int* __restrict__ cntp, const uint* __restrict__ edges,
             const ushort* __restrict__ hpan, const float* __restrict__ dinv,
             const float* __restrict__ bias, float* __restrict__ out,
             int F, int npan, int N) {
    aggr_body<true>(perm, rowptr, cntp, edges, hpan, dinv, bias, out, F, npan, N);
}

__global__ __launch_bounds__(256)
void k_aggr2(const ushort* __restrict__ perm, const int* __restrict__ rowptr,
             const int* __restrict__ cntp, const uint* __restrict__ edges,
             const ushort* __restrict__ hpan, const float* __restrict__ dinv,
             const float* __restrict__ bias, float* __restrict__ out,
             int F, int npan, int N) {
    aggr_body<false>(perm, rowptr, cntp, edges, hpan, dinv, bias, out, F, npan, N);
}

// ================= launcher =================

static inline char* bump(char*& p, size_t bytes) {
    char* r = p;
    p += (bytes + 255) & ~(size_t)255;
    return r;
}

extern "C" void kernel_launch(void* const* d_in, const int* in_sizes, int n_in,
                              void* d_out, int out_size, void* d_ws, size_t ws_size,
                              hipStream_t stream) {
    const float* x  = (const float*)d_in[0];
    const int*   ei = (const int*)d_in[1];
    const float* ew = (const float*)d_in[2];
    const float* W1 = (const float*)d_in[3];
    const float* b1 = (const float*)d_in[4];
    const float* W2 = (const float*)d_in[5];
    const float* b2 = (const float*)d_in[6];
    float* out = (float*)d_out;

    const int E    = in_sizes[2];
    const int H    = in_sizes[4];       // 256
    const int Fout = in_sizes[6];       // 128
    const int Fin  = in_sizes[3] / H;   // 256
    const int N    = in_sizes[0] / Fin; // 50000 (fits ushort)
    const int NB   = (N + 63) >> 6;     // buckets of 64 nodes (<= 1023)

    const int* row = ei;
    const int* col = ei + E;

    char* p = (char*)d_ws;
    float*  dinv   = (float*)bump(p, (size_t)N * 4);
    int*    cntp   = (int*)bump(p, (size_t)N * 4);
    int*    rowptr = (int*)bump(p, (size_t)N * 4);
    ushort* perm   = (ushort*)bump(p, (size_t)NBMAX * 64 * 2);
    uint*   edgesP = (uint*)bump(p, ((size_t)E + 3 * N + 192 * (size_t)NBMAX + 256) * 4);
    int*    counts = (int*)bump(p, (size_t)NBMAX * NBLK * 4);
    int*    btot   = (int*)bump(p, (size_t)NBMAX * 4);
    int*    bbase  = (int*)bump(p, (size_t)(NBMAX + 1) * 4);
    ushort* WT1h   = (ushort*)bump(p, (size_t)Fin * H * 2);
    ushort* WT1l   = (ushort*)bump(p, (size_t)Fin * H * 2);
    ushort* WT2h   = (ushort*)bump(p, (size_t)H * Fout * 2);
    ushort* WT2l   = (ushort*)bump(p, (size_t)H * Fout * 2);
    ushort* h1     = (ushort*)bump(p, (size_t)N * H * 2);     // panel-major bf16
    float*  a1     = (float*)bump(p, (size_t)N * H * 4);      // row-major fp32
    ushort* h2     = (ushort*)bump(p, (size_t)N * Fout * 2);  // panel-major bf16

    // recs overlays a1: consumed by binD_a/b before a1 is first written.
    ull* recs = (ull*)a1;

    const int sp1 = (Fin * H + 255) / 256;      // 256
    const int sp2 = (H * Fout + 255) / 256;     // 128
    const int gb1 = (H / 128) * ((N + 127) / 128);   // GEMM1 tiles (782)
    int T1 = gb1 < 280 ? gb1 : 280;
    int T2 = gb1 < 480 ? gb1 : 480;
    if (T2 < T1) T2 = T1;

    // stage A: edge histogram || weight split/transpose
    k_fusedA<<<NBLK + sp1 + sp2, 256, 0, stream>>>(col, counts, E, NB,
                                                   W1, WT1h, WT1l, Fin, H,
                                                   W2, WT2h, WT2l, Fout, sp1);
    k_scanB1<<<NB, 256, 0, stream>>>(counts, btot);
    k_scanB2<<<1, 256, 0, stream>>>(btot, bbase, NB);
    // stage B: bucket-sort || GEMM1 tiles [0,T1)
    k_fusedB1<<<NBLK + T1, 256, 0, stream>>>(row, col, ew, counts, bbase, recs, E, NB,
                                             x, WT1h, WT1l, h1, N, H, Fin, 0);
    // stage C: per-node counts/dinv/rowptr/rank-perm || GEMM1 tiles [T1,T2)
    k_fusedB2<<<NB + (T2 - T1), 256, 0, stream>>>(recs, bbase, cntp, dinv, rowptr, perm,
                                                  N, NB, x, WT1h, WT1l, h1, N, H, Fin, T1);
    // stage D: CSR emission || GEMM1 tiles [T2,gb1)
    k_fusedB3<<<NB + (gb1 - T2), 256, 0, stream>>>(recs, bbase, rowptr, cntp, dinv,
                                                   edgesP, N, NB,
                                                   x, WT1h, WT1l, h1, N, H, Fin, T2);

    const int chunks = (N + NPB - 1) / NPB;

    // layer 1 aggregation
    k_aggr1<<<chunks * (H / 32), 256, 0, stream>>>(perm, rowptr, cntp, edgesP, h1, dinv, b1, a1, H, H / 32, N);

    // layer 2
    k_gemm3<<<dim3(Fout / 128, (N + 127) / 128), 256, 0, stream>>>(a1, WT2h, WT2l, h2, N, Fout, H);
    k_aggr2<<<chunks * (Fout / 32), 256, 0, stream>>>(perm, rowptr, cntp, edgesP, h2, dinv, b2, out, Fout, Fout / 32, N);
}

// Round 13
// 407.703 us; speedup vs baseline: 2.1833x; 1.0030x over previous
//
#include <hip/hip_runtime.h>

typedef __attribute__((ext_vector_type(8))) short  short8;
typedef __attribute__((ext_vector_type(4))) float  f32x4;
typedef __attribute__((ext_vector_type(4))) ushort us4;
typedef __attribute__((ext_vector_type(4))) uint   u32x4;
typedef __attribute__((ext_vector_type(2))) uint   u32x2;
typedef unsigned long long ull;

__device__ __forceinline__ float bf2f(ushort u) {
    union { uint i; float f; } c; c.i = ((uint)u) << 16; return c.f;
}
__device__ __forceinline__ float bits2f(uint b) {
    union { uint i; float f; } c; c.i = b; return c.f;
}
__device__ __forceinline__ ushort f2bf(float f) {
    union { float f; uint i; } c; c.f = f;
    uint b = c.i + 0x7fffu + ((c.i >> 16) & 1u);   // RNE, no NaN inputs here
    return (ushort)(b >> 16);
}

// ================= CSR build via LDS-binned counting sort ====================
// Contiguous padded CSR. Bucket b's padded region statically starts at
// bbase[b] + 192*b (per-node x4 padding adds <= 3*64 slots per bucket), so
// binDa writes rowptr directly (no second bucket scan). binDa also rank-sorts
// nodes within its bucket in LDS (no global atomics — round-10 lesson: 50K
// atomics onto 64 global words serialized at the memory-side RMW units).
// Round-12 lesson: binC/histA at 256 blocks = 1 block/CU, each a serial
// ~600cy-per-edge chain; NBLK=512 halves that serial depth.
#define NBLK  512     // blocks for histA/binC
#define NBMAX 1024    // max buckets of 64 nodes (N <= 65472)

__device__ __forceinline__
void histA_body(const int* __restrict__ col, int* __restrict__ counts,
                int E, int NB, uint* hist) {
    for (int j = threadIdx.x; j < NB; j += 256) hist[j] = 0u;
    __syncthreads();
    for (int i = blockIdx.x * 256 + threadIdx.x; i < E; i += 256 * NBLK)
        atomicAdd(&hist[((uint)col[i]) >> 6], 1u);
    __syncthreads();
    for (int j = threadIdx.x; j < NB; j += 256)
        counts[j * NBLK + blockIdx.x] = (int)hist[j];
}

__device__ __forceinline__
void binC_body(const int* __restrict__ row, const int* __restrict__ col,
               const float* __restrict__ w,
               const int* __restrict__ counts, const int* __restrict__ bbase,
               ull* __restrict__ recs, int E, int NB, uint* cur) {
    for (int j = threadIdx.x; j < NB; j += 256)
        cur[j] = (uint)(bbase[j] + counts[j * NBLK + blockIdx.x]);
    __syncthreads();
    for (int i = blockIdx.x * 256 + threadIdx.x; i < E; i += 256 * NBLK) {
        int c = col[i], r = row[i];
        float wv = w[i];
        uint w16 = (uint)(wv * 65536.0f);
        if (w16 > 65535u) w16 = 65535u;
        uint pos = atomicAdd(&cur[((uint)c) >> 6], 1u);
        recs[pos] = ((ull)(uint)c << 32) | (ull)((w16 << 16) | (uint)(r & 0xffff));
    }
}

// per bucket: per-node count/wsum -> dinv, padded count, rowptr (static bucket
// base + local scan), and within-bucket degree-rank permutation (NO atomics).
__device__ __forceinline__
void binDa_body(const ull* __restrict__ recs, const int* __restrict__ bbase,
                int* __restrict__ cntp, float* __restrict__ dinv,
                int* __restrict__ rowptr, ushort* __restrict__ perm, int N,
                uint* cnt, uint* ws, uint* arr, uint* keys) {
    int b = blockIdx.x, t = threadIdx.x;
    if (t < 64) { cnt[t] = 0u; ws[t] = 0u; }
    __syncthreads();
    int lo = bbase[b], hi = bbase[b + 1];
    for (int i = lo + t; i < hi; i += 256) {
        ull rec = recs[i];
        atomicAdd(&cnt[((uint)(rec >> 32)) & 63u], 1u);
        atomicAdd(&ws[((uint)(rec >> 32)) & 63u], (uint)((rec >> 16) & 0xffffu));
    }
    __syncthreads();
    int node = b * 64 + t;
    uint cp = 0;
    if (t < 64) {
        if (node < N) cp = (cnt[t] + 3u) & ~3u;
        arr[t] = cp;
        keys[t] = (node < N) ? cp : 0xffffffffu;   // invalid nodes rank last
    }
    __syncthreads();
    for (int off = 1; off < 64; off <<= 1) {
        uint x = (t < 64 && t >= off) ? arr[t - off] : 0u;
        __syncthreads();
        if (t < 64) arr[t] += x;
        __syncthreads();
    }
    if (t < 64 && node < N) {
        int base = bbase[b] + 192 * b;
        rowptr[node] = base + (int)(arr[t] - cp);
        cntp[node]   = (int)cp;
        dinv[node]   = rsqrtf(1.0f + (float)ws[t] * (1.0f / 65536.0f));
        // stable within-bucket degree rank (64 broadcast compares, no atomics)
        uint key = keys[t];
        int rank = 0;
        #pragma unroll 8
        for (int j = 0; j < 64; ++j) {
            uint kj = keys[j];
            rank += (kj < key) || (kj == key && j < t);
        }
        perm[b * 64 + rank] = (ushort)node;
    }
}

// per bucket: place edges with packed bf16 norm at rowptr offsets; zero pads.
__device__ __forceinline__
void binDb_body(const ull* __restrict__ recs, const int* __restrict__ bbase,
                const int* __restrict__ rowptr, const int* __restrict__ cntp,
                const float* __restrict__ dinv, uint* __restrict__ edgesP, int N,
                uint* curN, uint* rbs, uint* cps) {
    int b = blockIdx.x, t = threadIdx.x;
    int node = b * 64 + t;
    if (t < 64) {
        uint rp = 0u, cp = 0u;
        if (node < N) { rp = (uint)rowptr[node]; cp = (uint)cntp[node]; }
        rbs[t] = rp; curN[t] = rp; cps[t] = cp;
    }
    __syncthreads();
    int lo = bbase[b], hi = bbase[b + 1];
    for (int i = lo + t; i < hi; i += 256) {
        ull rec = recs[i];
        uint c   = (uint)(rec >> 32);
        uint r   = (uint)rec & 0xffffu;
        uint w16 = ((uint)rec >> 16) & 0xffffu;
        float nv = dinv[r] * ((float)w16 * (1.0f / 65536.0f)) * dinv[c];
        uint slot = atomicAdd(&curN[c & 63u], 1u);
        edgesP[slot] = r | ((uint)f2bf(nv) << 16);
    }
    __syncthreads();
    if (t < 64 && node < N) {
        uint e1 = rbs[t] + cps[t];
        for (uint j = curN[t]; j < e1; ++j) edgesP[j] = 0u;  // nv=0, r=0 pad
    }
}

// exclusive scan of counts[b][0..511] in place (2 per thread); totals out.
__global__ void k_scanB1(int* __restrict__ counts, int* __restrict__ btot) {
    __shared__ int s[256];
    int b = blockIdx.x, t = threadIdx.x;
    int v0 = counts[b * NBLK + 2 * t];
    int v1 = counts[b * NBLK + 2 * t + 1];
    int sum = v0 + v1;
    s[t] = sum; __syncthreads();
    for (int off = 1; off < 256; off <<= 1) {
        int x = (t >= off) ? s[t - off] : 0;
        __syncthreads();
        s[t] += x;
        __syncthreads();
    }
    int excl = s[t] - sum;
    counts[b * NBLK + 2 * t]     = excl;
    counts[b * NBLK + 2 * t + 1] = excl + v0;
    if (t == 255) btot[b] = s[255];
}

// exclusive scan of up to 1023 totals -> base[0..NB].
__global__ void k_scanB2(const int* __restrict__ btot, int* __restrict__ bbase, int NB) {
    __shared__ int s[256];
    int t = threadIdx.x;
    int v[4]; int sum = 0;
    #pragma unroll
    for (int j = 0; j < 4; ++j) {
        int i = t * 4 + j;
        v[j] = (i < NB) ? btot[i] : 0;
        sum += v[j];
    }
    s[t] = sum; __syncthreads();
    for (int off = 1; off < 256; off <<= 1) {
        int x = (t >= off) ? s[t - off] : 0;
        __syncthreads();
        s[t] += x;
        __syncthreads();
    }
    int excl = s[t] - sum;
    #pragma unroll
    for (int j = 0; j < 4; ++j) {
        int i = t * 4 + j;
        if (i <= NB) bbase[i] = excl;
        excl += v[j];
    }
}

// ================= weight split + transpose: W[K][N] -> WT{h,l}[N][K] ==========
__device__ __forceinline__
void splitT_body(const float* __restrict__ W, ushort* __restrict__ Th,
                 ushort* __restrict__ Tl, int K, int N, int i) {
    if (i < K * N) {
        int k = i / N, n = i - k * N;
        float v = W[i];
        ushort hi = f2bf(v);
        ushort lo = f2bf(v - bf2f(hi));
        Th[(size_t)n * K + k] = hi;
        Tl[(size_t)n * K + k] = lo;
    }
}

// ================= MFMA GEMM core =============================================
// Tile 128x128, BK=32, 256 thr = 4 waves (2x2), wave = 64x64 = 4x4 MFMA tiles.
// 3-product split precision: Ah*Bh + Ah*Bl + Al*Bh.
#define LDA 40   // padded LDS row stride (bf16 elems); 80 B = 5*16 keeps 16B align

__device__ __forceinline__
void gemm3_body(const float* __restrict__ A, const ushort* __restrict__ BTh,
                const ushort* __restrict__ BTl, ushort* __restrict__ Cpan,
                int M, int Nc, int K, int bm, int bn,
                ushort (*As)[128][LDA], ushort (*Bs)[128][LDA]) {
    const int t    = threadIdx.x;
    const int lane = t & 63;
    const int wid  = t >> 6;
    const int wm   = wid >> 1;
    const int wn   = wid & 1;
    const int ml   = lane & 15;
    const int kq   = lane >> 4;

    f32x4 acc[4][4];
    #pragma unroll
    for (int mt = 0; mt < 4; ++mt)
        #pragma unroll
        for (int nt = 0; nt < 4; ++nt) acc[mt][nt] = (f32x4){0.f, 0.f, 0.f, 0.f};

    for (int k0 = 0; k0 < K; k0 += 32) {
        #pragma unroll
        for (int it = 0; it < 4; ++it) {
            int idx = (t + it * 256) * 4;
            int r  = idx >> 5;
            int kk = idx & 31;
            int grow = bm + r;
            f32x4 v = (f32x4){0.f, 0.f, 0.f, 0.f};
            if (grow < M) v = *(const f32x4*)&A[(size_t)grow * K + k0 + kk];
            us4 hi, lo;
            #pragma unroll
            for (int j = 0; j < 4; ++j) {
                ushort h = f2bf(v[j]);
                hi[j] = h;
                lo[j] = f2bf(v[j] - bf2f(h));
            }
            *(us4*)&As[0][r][kk] = hi;
            *(us4*)&As[1][r][kk] = lo;
        }
        #pragma unroll
        for (int it = 0; it < 2; ++it) {
            int idx = (t + it * 256) * 8;
            int n  = idx >> 5;
            int kk = idx & 31;
            u32x4 vh = *(const u32x4*)&BTh[(size_t)(bn + n) * K + k0 + kk];
            *(u32x4*)&Bs[0][n][kk] = vh;
            u32x4 vl = *(const u32x4*)&BTl[(size_t)(bn + n) * K + k0 + kk];
            *(u32x4*)&Bs[1][n][kk] = vl;
        }
        __syncthreads();

        short8 a[4][2], b[4][2];
        #pragma unroll
        for (int mt = 0; mt < 4; ++mt) {
            a[mt][0] = *(const short8*)&As[0][wm * 64 + mt * 16 + ml][kq * 8];
            a[mt][1] = *(const short8*)&As[1][wm * 64 + mt * 16 + ml][kq * 8];
        }
        #pragma unroll
        for (int nt = 0; nt < 4; ++nt) {
            b[nt][0] = *(const short8*)&Bs[0][wn * 64 + nt * 16 + ml][kq * 8];
            b[nt][1] = *(const short8*)&Bs[1][wn * 64 + nt * 16 + ml][kq * 8];
        }
        #pragma unroll
        for (int mt = 0; mt < 4; ++mt)
            #pragma unroll
            for (int nt = 0; nt < 4; ++nt) {
                acc[mt][nt] = __builtin_amdgcn_mfma_f32_16x16x32_bf16(a[mt][0], b[nt][0], acc[mt][nt], 0, 0, 0);
                acc[mt][nt] = __builtin_amdgcn_mfma_f32_16x16x32_bf16(a[mt][0], b[nt][1], acc[mt][nt], 0, 0, 0);
                acc[mt][nt] = __builtin_amdgcn_mfma_f32_16x16x32_bf16(a[mt][1], b[nt][0], acc[mt][nt], 0, 0, 0);
            }
        __syncthreads();
    }

    #pragma unroll
    for (int mt = 0; mt < 4; ++mt) {
        int rbase = bm + wm * 64 + mt * 16 + kq * 4;
        #pragma unroll
        for (int nt = 0; nt < 4; ++nt) {
            int colg = bn + wn * 64 + nt * 16 + ml;
            size_t pbase = (size_t)(colg >> 5) * M * 32 + (colg & 31);
            #pragma unroll
            for (int r = 0; r < 4; ++r) {
                int rr = rbase + r;
                if (rr < M) Cpan[pbase + (size_t)rr * 32] = f2bf(acc[mt][nt][r]);
            }
        }
    }
}

__global__ __launch_bounds__(256)
void k_gemm3(const float* __restrict__ A, const ushort* __restrict__ BTh,
             const ushort* __restrict__ BTl, ushort* __restrict__ Cpan,
             int M, int Nc, int K) {
    __shared__ __align__(16) ushort As[2][128][LDA];
    __shared__ __align__(16) ushort Bs[2][128][LDA];
    gemm3_body(A, BTh, BTl, Cpan, M, Nc, K, blockIdx.y * 128, blockIdx.x * 128, As, Bs);
}

// ================= fused launches (binning || GEMM1 tiles) ===================
__global__ __launch_bounds__(256)
void k_fusedA(const int* __restrict__ col, int* __restrict__ counts, int E, int NB,
              const float* __restrict__ W1, ushort* __restrict__ WT1h, ushort* __restrict__ WT1l,
              int Fin, int H,
              const float* __restrict__ W2, ushort* __restrict__ WT2h, ushort* __restrict__ WT2l,
              int Fout, int sp1) {
    __shared__ uint hist[NBMAX];
    int bid = (int)blockIdx.x;
    if (bid < NBLK) { histA_body(col, counts, E, NB, hist); return; }
    if (bid < NBLK + sp1) { splitT_body(W1, WT1h, WT1l, Fin, H, (bid - NBLK) * 256 + (int)threadIdx.x); return; }
    splitT_body(W2, WT2h, WT2l, H, Fout, (bid - NBLK - sp1) * 256 + (int)threadIdx.x);
}

__global__ __launch_bounds__(256)
void k_fusedB1(const int* __restrict__ row, const int* __restrict__ col,
               const float* __restrict__ w, const int* __restrict__ counts,
               const int* __restrict__ bbase, ull* __restrict__ recs, int E, int NB,
               const float* __restrict__ A, const ushort* __restrict__ BTh,
               const ushort* __restrict__ BTl, ushort* __restrict__ Cpan,
               int M, int Nc, int K, int t0) {
    __shared__ __align__(16) ushort As[2][128][LDA];
    __shared__ __align__(16) ushort Bs[2][128][LDA];
    int bid = (int)blockIdx.x;
    if (bid < NBLK) { binC_body(row, col, w, counts, bbase, recs, E, NB, (uint*)&As[0][0][0]); return; }
    int tile = t0 + bid - NBLK;
    int nbn = Nc >> 7;
    gemm3_body(A, BTh, BTl, Cpan, M, Nc, K, (tile / nbn) * 128, (tile % nbn) * 128, As, Bs);
}

__global__ __launch_bounds__(256)
void k_fusedB2(const ull* __restrict__ recs, const int* __restrict__ bbase,
               int* __restrict__ cntp, float* __restrict__ dinv,
               int* __restrict__ rowptr, ushort* __restrict__ perm,
               int N, int NB,
               const float* __restrict__ A, const ushort* __restrict__ BTh,
               const ushort* __restrict__ BTl, ushort* __restrict__ Cpan,
               int M, int Nc, int K, int t0) {
    __shared__ __align__(16) ushort As[2][128][LDA];
    __shared__ __align__(16) ushort Bs[2][128][LDA];
    int bid = (int)blockIdx.x;
    if (bid < NB) {
        uint* l = (uint*)&As[0][0][0];
        binDa_body(recs, bbase, cntp, dinv, rowptr, perm, N, l, l + 64, l + 128, l + 192);
        return;
    }
    int tile = t0 + bid - NB;
    int nbn = Nc >> 7;
    gemm3_body(A, BTh, BTl, Cpan, M, Nc, K, (tile / nbn) * 128, (tile % nbn) * 128, As, Bs);
}

__global__ __launch_bounds__(256)
void k_fusedB3(const ull* __restrict__ recs, const int* __restrict__ bbase,
               const int* __restrict__ rowptr, const int* __restrict__ cntp,
               const float* __restrict__ dinv, uint* __restrict__ edgesP,
               int N, int NB,
               const float* __restrict__ A, const ushort* __restrict__ BTh,
               const ushort* __restrict__ BTl, ushort* __restrict__ Cpan,
               int M, int Nc, int K, int t0) {
    __shared__ __align__(16) ushort As[2][128][LDA];
    __shared__ __align__(16) ushort Bs[2][128][LDA];
    int bid = (int)blockIdx.x;
    if (bid < NB) {
        uint* l = (uint*)&As[0][0][0];
        binDb_body(recs, bbase, rowptr, cntp, dinv, edgesP, N, l, l + 64, l + 128);
        return;
    }
    int tile = t0 + bid - NB;
    int nbn = Nc >> 7;
    gemm3_body(A, BTh, BTl, Cpan, M, Nc, K, (tile / nbn) * 128, (tile % nbn) * 128, As, Bs);
}

// ================= panel CSR aggregation, butterfly-free =====================
// Panel-per-block (p = bid % npan): consecutive blocks round-robin XCDs so each
// XCD's L2 holds ONE 3.2 MB panel. Lanes: g=lane>>2 (16 nodes/wave), c=lane&3
// (8 feats/lane, one 16B dwordx4 gather; 4 lanes cover one 64B row).
// Round-12 lesson: 2-deep x 4-edge pipeline (8 gathers in flight) only bought
// 3% — widen to 8 edges/iteration (2 packets), still 2-deep: 16 gathers in
// flight per lane and half the loop-control per edge. All pipeline registers
// named. Loads past the segment end are guarded to zero packets (nv=0, r=0),
// so no consumption guards are needed.
#define NPB 64   // nodes per block: 4 waves x 16 nodes

#define GATHER(pk) (*(const u32x4*)(hp + (size_t)((pk) & 0xffffu) * 32))
#define CONSUME(pk, hv)                                              \
    {                                                                \
        float nv = bits2f((pk) & 0xffff0000u);                       \
        _Pragma("unroll")                                            \
        for (int q = 0; q < 4; ++q) {                                \
            acc[2 * q]     += nv * bits2f((hv)[q] << 16);            \
            acc[2 * q + 1] += nv * bits2f((hv)[q] & 0xffff0000u);    \
        }                                                            \
    }

template <bool RELU>
__device__ __forceinline__
void aggr_body(const ushort* __restrict__ perm, const int* __restrict__ rowptr,
               const int* __restrict__ cntp, const uint* __restrict__ edges,
               const ushort* __restrict__ hpan, const float* __restrict__ dinv,
               const float* __restrict__ bias, float* __restrict__ out,
               int F, int npan, int N) {
    const int bid  = blockIdx.x;
    const int p    = bid % npan;
    const int wave = threadIdx.x >> 6;
    const int lane = threadIdx.x & 63;
    const int g    = lane >> 2;        // node slot within wave (0..15)
    const int c    = lane & 3;         // feature octet within panel (0..3)
    const int idx  = (bid / npan) * NPB + wave * 16 + g;
    const int fbase = p * 32 + c * 8;

    const ushort* hp = hpan + (size_t)p * N * 32 + c * 8;   // + r*32 per gather

    int node = 0, beg = 0, end = 0;
    if (idx < N) {
        node = (int)perm[idx];
        beg = rowptr[node];
        end = beg + cntp[node];
    }

    float acc[8] = {};
    const u32x4 Z = (u32x4){0u, 0u, 0u, 0u};
    int e0 = beg;
    u32x4 pkA0 = Z, pkA1 = Z, pkB0 = Z, pkB1 = Z;
    if (e0      < end) pkA0 = *(const u32x4*)&edges[e0];
    if (e0 +  4 < end) pkA1 = *(const u32x4*)&edges[e0 + 4];
    if (e0 +  8 < end) pkB0 = *(const u32x4*)&edges[e0 + 8];
    if (e0 + 12 < end) pkB1 = *(const u32x4*)&edges[e0 + 12];
    // issue group-A gathers (r=0 for zero packets -> harmless row-0 read)
    u32x4 hvA0 = GATHER(pkA0[0]), hvA1 = GATHER(pkA0[1]);
    u32x4 hvA2 = GATHER(pkA0[2]), hvA3 = GATHER(pkA0[3]);
    u32x4 hvA4 = GATHER(pkA1[0]), hvA5 = GATHER(pkA1[1]);
    u32x4 hvA6 = GATHER(pkA1[2]), hvA7 = GATHER(pkA1[3]);

    while (__any(e0 < end)) {
        // prefetch group C (two groups ahead)
        u32x4 pkC0 = Z, pkC1 = Z;
        if (e0 + 16 < end) pkC0 = *(const u32x4*)&edges[e0 + 16];
        if (e0 + 20 < end) pkC1 = *(const u32x4*)&edges[e0 + 20];
        // issue group-B gathers before consuming group A
        u32x4 hvB0 = GATHER(pkB0[0]), hvB1 = GATHER(pkB0[1]);
        u32x4 hvB2 = GATHER(pkB0[2]), hvB3 = GATHER(pkB0[3]);
        u32x4 hvB4 = GATHER(pkB1[0]), hvB5 = GATHER(pkB1[1]);
        u32x4 hvB6 = GATHER(pkB1[2]), hvB7 = GATHER(pkB1[3]);
        // consume group A (zero packets add zero)
        CONSUME(pkA0[0], hvA0); CONSUME(pkA0[1], hvA1);
        CONSUME(pkA0[2], hvA2); CONSUME(pkA0[3], hvA3);
        CONSUME(pkA1[0], hvA4); CONSUME(pkA1[1], hvA5);
        CONSUME(pkA1[2], hvA6); CONSUME(pkA1[3], hvA7);
        // rotate pipeline registers (all named — no runtime indexing)
        pkA0 = pkB0; pkA1 = pkB1; pkB0 = pkC0; pkB1 = pkC1;
        hvA0 = hvB0; hvA1 = hvB1; hvA2 = hvB2; hvA3 = hvB3;
        hvA4 = hvB4; hvA5 = hvB5; hvA6 = hvB6; hvA7 = hvB7;
        e0 += 8;
    }

    if (idx < N) {
        float di = dinv[node];
        float d2 = di * di;
        u32x4 hs = *(const u32x4*)(hp + (size_t)node * 32);
        f32x4 bv0 = *(const f32x4*)&bias[fbase];
        f32x4 bv1 = *(const f32x4*)&bias[fbase + 4];
        f32x4 v0, v1;
        #pragma unroll
        for (int q = 0; q < 4; ++q) {
            float r0 = acc[2 * q]     + d2 * bits2f(hs[q] << 16)
                     + ((q < 2) ? bv0[2 * q] : bv1[2 * q - 4]);
            float r1 = acc[2 * q + 1] + d2 * bits2f(hs[q] & 0xffff0000u)
                     + ((q < 2) ? bv0[2 * q + 1] : bv1[2 * q - 3]);
            if (RELU) { r0 = fmaxf(r0, 0.f); r1 = fmaxf(r1, 0.f); }
            if (q < 2) { v0[2 * q] = r0; v0[2 * q + 1] = r1; }
            else       { v1[2 * q - 4] = r0; v1[2 * q - 3] = r1; }
        }
        *(f32x4*)&out[(size_t)node * F + fbase]     = v0;
        *(f32x4*)&out[(size_t)node * F + fbase + 4] = v1;
    }
}

__global__ __launch_bounds__(256)
void k_aggr1(const ushort* __restrict__ perm, const int* __restrict__ rowptr,
             const int* __restrict__ cntp, const uint* __restrict__ edges,
             const ushort* __restrict__ hpan, const float* __restrict__ dinv,
             const float* __restrict__ bias, float* __restrict__ out,
             int F, int npan, int N) {
    aggr_body<true>(perm, rowptr, cntp, edges, hpan, dinv, bias, out, F, npan, N);
}

__global__ __launch_bounds__(256)
void k_aggr2(const ushort* __restrict__ perm, const int* __restrict__ rowptr,
             const int* __restrict__ cntp, const uint* __restrict__ edges,
             const ushort* __restrict__ hpan, const float* __restrict__ dinv,
             const float* __restrict__ bias, float* __restrict__ out,
             int F, int npan, int N) {
    aggr_body<false>(perm, rowptr, cntp, edges, hpan, dinv, bias, out, F, npan, N);
}

// ================= launcher =================

static inline char* bump(char*& p, size_t bytes) {
    char* r = p;
    p += (bytes + 255) & ~(size_t)255;
    return r;
}

extern "C" void kernel_launch(void* const* d_in, const int* in_sizes, int n_in,
                              void* d_out, int out_size, void* d_ws, size_t ws_size,
                              hipStream_t stream) {
    const float* x  = (const float*)d_in[0];
    const int*   ei = (const int*)d_in[1];
    const float* ew = (const float*)d_in[2];
    const float* W1 = (const float*)d_in[3];
    const float* b1 = (const float*)d_in[4];
    const float* W2 = (const float*)d_in[5];
    const float* b2 = (const float*)d_in[6];
    float* out = (float*)d_out;

    const int E    = in_sizes[2];
    const int H    = in_sizes[4];       // 256
    const int Fout = in_sizes[6];       // 128
    const int Fin  = in_sizes[3] / H;   // 256
    const int N    = in_sizes[0] / Fin; // 50000 (fits ushort)
    const int NB   = (N + 63) >> 6;     // buckets of 64 nodes (<= 1023)

    const int* row = ei;
    const int* col = ei + E;

    char* p = (char*)d_ws;
    float*  dinv   = (float*)bump(p, (size_t)N * 4);
    int*    cntp   = (int*)bump(p, (size_t)N * 4);
    int*    rowptr = (int*)bump(p, (size_t)N * 4);
    ushort* perm   = (ushort*)bump(p, (size_t)NBMAX * 64 * 2);
    uint*   edgesP = (uint*)bump(p, ((size_t)E + 3 * N + 192 * (size_t)NBMAX + 256) * 4);
    int*    counts = (int*)bump(p, (size_t)NBMAX * NBLK * 4);
    int*    btot   = (int*)bump(p, (size_t)NBMAX * 4);
    int*    bbase  = (int*)bump(p, (size_t)(NBMAX + 1) * 4);
    ushort* WT1h   = (ushort*)bump(p, (size_t)Fin * H * 2);
    ushort* WT1l   = (ushort*)bump(p, (size_t)Fin * H * 2);
    ushort* WT2h   = (ushort*)bump(p, (size_t)H * Fout * 2);
    ushort* WT2l   = (ushort*)bump(p, (size_t)H * Fout * 2);
    ushort* h1     = (ushort*)bump(p, (size_t)N * H * 2);     // panel-major bf16
    float*  a1     = (float*)bump(p, (size_t)N * H * 4);      // row-major fp32
    ushort* h2     = (ushort*)bump(p, (size_t)N * Fout * 2);  // panel-major bf16

    // recs overlays a1: consumed by binD_a/b before a1 is first written.
    ull* recs = (ull*)a1;

    const int sp1 = (Fin * H + 255) / 256;      // 256
    const int sp2 = (H * Fout + 255) / 256;     // 128
    const int gb1 = (H / 128) * ((N + 127) / 128);   // GEMM1 tiles (782)
    int T1 = gb1 < 280 ? gb1 : 280;
    int T2 = gb1 < 480 ? gb1 : 480;
    if (T2 < T1) T2 = T1;

    // stage A: edge histogram || weight split/transpose
    k_fusedA<<<NBLK + sp1 + sp2, 256, 0, stream>>>(col, counts, E, NB,
                                                   W1, WT1h, WT1l, Fin, H,
                                                   W2, WT2h, WT2l, Fout, sp1);
    k_scanB1<<<NB, 256, 0, stream>>>(counts, btot);
    k_scanB2<<<1, 256, 0, stream>>>(btot, bbase, NB);
    // stage B: bucket-sort || GEMM1 tiles [0,T1)
    k_fusedB1<<<NBLK + T1, 256, 0, stream>>>(row, col, ew, counts, bbase, recs, E, NB,
                                             x, WT1h, WT1l, h1, N, H, Fin, 0);
    // stage C: per-node counts/dinv/rowptr/rank-perm || GEMM1 tiles [T1,T2)
    k_fusedB2<<<NB + (T2 - T1), 256, 0, stream>>>(recs, bbase, cntp, dinv, rowptr, perm,
                                                  N, NB, x, WT1h, WT1l, h1, N, H, Fin, T1);
    // stage D: CSR emission || GEMM1 tiles [T2,gb1)
    k_fusedB3<<<NB + (gb1 - T2), 256, 0, stream>>>(recs, bbase, rowptr, cntp, dinv,
                                                   edgesP, N, NB,
                                                   x, WT1h, WT1l, h1, N, H, Fin, T2);

    const int chunks = (N + NPB - 1) / NPB;

    // layer 1 aggregation
    k_aggr1<<<chunks * (H / 32), 256, 0, stream>>>(perm, rowptr, cntp, edgesP, h1, dinv, b1, a1, H, H / 32, N);

    // layer 2
    k_gemm3<<<dim3(Fout / 128, (N + 127) / 128), 256, 0, stream>>>(a1, WT2h, WT2l, h2, N, Fout, H);
    k_aggr2<<<chunks * (Fout / 32), 256, 0, stream>>>(perm, rowptr, cntp, edgesP, h2, dinv, b2, out, Fout, Fout / 32, N);
}